// Round 1
// baseline (3657.174 us; speedup 1.0000x reference)
//
#include <hip/hip_runtime.h>
#include <cstdint>
#include <cstddef>

#define B_    4
#define N_    1024
#define P_    128
#define D_    512
#define NH_   8
#define DH_   64
#define DQ_   256   // 4*DH
#define DFFN_ 2048

// ---------------------------------------------------------------------------
// LayerNorm: one block per row of 512, optional output row stride
// ---------------------------------------------------------------------------
__global__ __launch_bounds__(256) void ln_kernel(
    const float* __restrict__ x, const float* __restrict__ g,
    const float* __restrict__ bb, float* __restrict__ y, int ostride)
{
  int row = blockIdx.x;
  int t = threadIdx.x;
  const float* xr = x + (size_t)row * D_;
  float a = xr[t], c = xr[t + 256];
  float s = a + c, sq = a * a + c * c;
#pragma unroll
  for (int off = 32; off >= 1; off >>= 1) {
    s  += __shfl_xor(s, off);
    sq += __shfl_xor(sq, off);
  }
  __shared__ float ws_[8];
  int w = t >> 6, lane = t & 63;
  if (lane == 0) { ws_[w] = s; ws_[4 + w] = sq; }
  __syncthreads();
  float st  = ws_[0] + ws_[1] + ws_[2] + ws_[3];
  float sqt = ws_[4] + ws_[5] + ws_[6] + ws_[7];
  float mean = st * (1.0f / D_);
  float var  = sqt * (1.0f / D_) - mean * mean;
  float inv  = rsqrtf(var + 1e-5f);
  y[(size_t)row * ostride + t]       = (a - mean) * inv * g[t] + bb[t];
  y[(size_t)row * ostride + t + 256] = (c - mean) * inv * g[t + 256] + bb[t + 256];
}

// ---------------------------------------------------------------------------
// GEMM: C[M,N] = A[M,K] @ W[N,K]^T (+bias) (silu) (+res).  128x128 tile,
// BK=16, 256 threads, 8x8 microtile.  All M%128==0, N%128==0, K%16==0.
// flags: 1=bias, 2=res, 4=silu (applied after bias, before res)
// ---------------------------------------------------------------------------
__global__ __launch_bounds__(256) void gemm_kernel(
    const float* __restrict__ A, const float* __restrict__ W,
    const float* __restrict__ bias, const float* __restrict__ res,
    float* __restrict__ C, int M, int N, int K, int flags)
{
  __shared__ float As[16][132];
  __shared__ float Ws[16][132];
  const int t  = threadIdx.x;
  const int tx = t & 15, ty = t >> 4;
  const size_t row0 = (size_t)blockIdx.y * 128;
  const size_t col0 = (size_t)blockIdx.x * 128;
  const int lr = t >> 1;          // 0..127
  const int lc = (t & 1) * 8;     // 0 or 8
  const float* Ap = A + (row0 + lr) * (size_t)K + lc;
  const float* Wp = W + (col0 + lr) * (size_t)K + lc;
  float acc[8][8];
#pragma unroll
  for (int i = 0; i < 8; ++i)
#pragma unroll
    for (int j = 0; j < 8; ++j) acc[i][j] = 0.f;

  for (int k0 = 0; k0 < K; k0 += 16) {
    float4 a0 = *(const float4*)(Ap + k0);
    float4 a1 = *(const float4*)(Ap + k0 + 4);
    float4 w0 = *(const float4*)(Wp + k0);
    float4 w1 = *(const float4*)(Wp + k0 + 4);
    __syncthreads();
    As[lc + 0][lr] = a0.x; As[lc + 1][lr] = a0.y; As[lc + 2][lr] = a0.z; As[lc + 3][lr] = a0.w;
    As[lc + 4][lr] = a1.x; As[lc + 5][lr] = a1.y; As[lc + 6][lr] = a1.z; As[lc + 7][lr] = a1.w;
    Ws[lc + 0][lr] = w0.x; Ws[lc + 1][lr] = w0.y; Ws[lc + 2][lr] = w0.z; Ws[lc + 3][lr] = w0.w;
    Ws[lc + 4][lr] = w1.x; Ws[lc + 5][lr] = w1.y; Ws[lc + 6][lr] = w1.z; Ws[lc + 7][lr] = w1.w;
    __syncthreads();
#pragma unroll
    for (int kk = 0; kk < 16; ++kk) {
      float4 aA = *(const float4*)&As[kk][ty * 8];
      float4 aB = *(const float4*)&As[kk][ty * 8 + 4];
      float4 bA = *(const float4*)&Ws[kk][tx * 8];
      float4 bB = *(const float4*)&Ws[kk][tx * 8 + 4];
      float av[8] = {aA.x, aA.y, aA.z, aA.w, aB.x, aB.y, aB.z, aB.w};
      float bv[8] = {bA.x, bA.y, bA.z, bA.w, bB.x, bB.y, bB.z, bB.w};
#pragma unroll
      for (int i = 0; i < 8; ++i)
#pragma unroll
        for (int j = 0; j < 8; ++j)
          acc[i][j] += av[i] * bv[j];
    }
  }

#pragma unroll
  for (int i = 0; i < 8; ++i) {
    size_t m = row0 + (size_t)ty * 8 + i;
#pragma unroll
    for (int jq = 0; jq < 2; ++jq) {
      size_t n = col0 + (size_t)tx * 8 + jq * 4;
      float o[4] = {acc[i][jq * 4 + 0], acc[i][jq * 4 + 1],
                    acc[i][jq * 4 + 2], acc[i][jq * 4 + 3]};
      if (flags & 1) {
        float4 bv4 = *(const float4*)(bias + n);
        o[0] += bv4.x; o[1] += bv4.y; o[2] += bv4.z; o[3] += bv4.w;
      }
      if (flags & 4) {
#pragma unroll
        for (int q = 0; q < 4; ++q) o[q] = o[q] / (1.f + __expf(-o[q]));
      }
      if (flags & 2) {
        float4 rv = *(const float4*)(res + m * (size_t)N + n);
        o[0] += rv.x; o[1] += rv.y; o[2] += rv.z; o[3] += rv.w;
      }
      *(float4*)(C + m * (size_t)N + n) = make_float4(o[0], o[1], o[2], o[3]);
    }
  }
}

// ---------------------------------------------------------------------------
// Self-attention, fused: per (b,h, 8-query block).  Scores (8x1024) live in
// LDS; softmax with mask & bias; PV over concat(Hv, Vv) split outputs.
// ---------------------------------------------------------------------------
__global__ __launch_bounds__(256) void attn_self_kernel(
    const float* __restrict__ Hq, const float* __restrict__ Hk,
    const float* __restrict__ Hv, const float* __restrict__ Vvt,
    const float* __restrict__ Db, const float* __restrict__ rbf,
    const int* __restrict__ mask,
    float* __restrict__ Hres, float* __restrict__ Vres)
{
  const int bh = blockIdx.y, b = bh >> 3, h = bh & 7;
  const int n0 = blockIdx.x * 8;
  const int t = threadIdx.x;
  __shared__ float qs[8][DQ_];     // 8 KB
  __shared__ float ss[8][N_];      // 32 KB
  __shared__ float rowsum[8];

#pragma unroll
  for (int e = 0; e < 8; ++e) {
    int idx = e * 256 + t;
    int r = idx >> 8, d = idx & 255;
    qs[r][d] = Hq[(((size_t)b * N_ + n0 + r) * NH_ + h) * DQ_ + d];
  }
  __syncthreads();

  const float factor = 0.0625f;    // 0.5/sqrt(64)
  const size_t bias_base = (size_t)b * N_ * N_;
  {
    const float* kp0 = Hk + (((size_t)b * N_ + (t       )) * NH_ + h) * DQ_;
    const float* kp1 = Hk + (((size_t)b * N_ + (t +  256)) * NH_ + h) * DQ_;
    const float* kp2 = Hk + (((size_t)b * N_ + (t +  512)) * NH_ + h) * DQ_;
    const float* kp3 = Hk + (((size_t)b * N_ + (t +  768)) * NH_ + h) * DQ_;
    float acc[4][8];
#pragma unroll
    for (int j = 0; j < 4; ++j)
#pragma unroll
      for (int r = 0; r < 8; ++r) acc[j][r] = 0.f;
    for (int d = 0; d < DQ_; d += 4) {
      float4 kv0 = *(const float4*)(kp0 + d);
      float4 kv1 = *(const float4*)(kp1 + d);
      float4 kv2 = *(const float4*)(kp2 + d);
      float4 kv3 = *(const float4*)(kp3 + d);
#pragma unroll
      for (int r = 0; r < 8; ++r) {
        float q0 = qs[r][d], q1 = qs[r][d + 1], q2 = qs[r][d + 2], q3 = qs[r][d + 3];
        acc[0][r] += kv0.x * q0 + kv0.y * q1 + kv0.z * q2 + kv0.w * q3;
        acc[1][r] += kv1.x * q0 + kv1.y * q1 + kv1.z * q2 + kv1.w * q3;
        acc[2][r] += kv2.x * q0 + kv2.y * q1 + kv2.z * q2 + kv2.w * q3;
        acc[3][r] += kv3.x * q0 + kv3.y * q1 + kv3.z * q2 + kv3.w * q3;
      }
    }
#pragma unroll
    for (int j = 0; j < 4; ++j) {
      int m = t + j * 256;
      int mk = mask[b * N_ + m];
#pragma unroll
      for (int r = 0; r < 8; ++r) {
        float sv = mk ? (acc[j][r] * factor
                         + rbf[bias_base + (size_t)(n0 + r) * N_ + m]
                         + Db [bias_base + (size_t)(n0 + r) * N_ + m])
                      : -INFINITY;
        ss[r][m] = sv;
      }
    }
  }
  __syncthreads();

  {
    int r = t >> 5, i = t & 31;
    float mx = -INFINITY;
    for (int m = i; m < N_; m += 32) mx = fmaxf(mx, ss[r][m]);
#pragma unroll
    for (int off = 16; off >= 1; off >>= 1) mx = fmaxf(mx, __shfl_xor(mx, off));
    float sm = 0.f;
    for (int m = i; m < N_; m += 32) {
      float p = __expf(ss[r][m] - mx);
      ss[r][m] = p;
      sm += p;
    }
#pragma unroll
    for (int off = 16; off >= 1; off >>= 1) sm += __shfl_xor(sm, off);
    if (i == 0) rowsum[r] = sm;
  }
  __syncthreads();

  {
    int r = t >> 5;
    int d0 = (t & 31) * 8;
    const float* vbase;
    size_t vstride;
    int c = 0, j0 = 0;
    if (d0 < 64) {
      vbase = Hv + ((size_t)b * N_) * D_ + h * 64 + d0;
      vstride = D_;
    } else {
      int dd = d0 - 64; c = dd >> 6; j0 = dd & 63;
      vbase = Vvt + (((size_t)b * N_) * 3 + c) * D_ + h * 64 + j0;
      vstride = 3 * D_;
    }
    float o0 = 0, o1 = 0, o2 = 0, o3 = 0, o4 = 0, o5 = 0, o6 = 0, o7 = 0;
#pragma unroll 2
    for (int m = 0; m < N_; ++m) {
      float p = ss[r][m];
      const float* vp = vbase + (size_t)m * vstride;
      float4 x = *(const float4*)vp;
      float4 y = *(const float4*)(vp + 4);
      o0 += p * x.x; o1 += p * x.y; o2 += p * x.z; o3 += p * x.w;
      o4 += p * y.x; o5 += p * y.y; o6 += p * y.z; o7 += p * y.w;
    }
    float inv = 1.0f / rowsum[r];
    int n = n0 + r;
    if (d0 < 64) {
      float* op = Hres + ((size_t)b * N_ + n) * D_ + h * 64 + d0;
      *(float4*)op       = make_float4(o0 * inv, o1 * inv, o2 * inv, o3 * inv);
      *(float4*)(op + 4) = make_float4(o4 * inv, o5 * inv, o6 * inv, o7 * inv);
    } else {
      float* op = Vres + (((size_t)b * N_ + n) * 3 + c) * D_ + h * 64 + j0;
      *(float4*)op       = make_float4(o0 * inv, o1 * inv, o2 * inv, o3 * inv);
      *(float4*)(op + 4) = make_float4(o4 * inv, o5 * inv, o6 * inv, o7 * inv);
    }
  }
}

// ---------------------------------------------------------------------------
// Cross-attention: one wave per (b,h,n), P=128 keys, DH=64.
// ---------------------------------------------------------------------------
__global__ __launch_bounds__(256) void attn_cross_kernel(
    const float* __restrict__ q, const float* __restrict__ k,
    const float* __restrict__ v, float* __restrict__ co)
{
  const int bh = blockIdx.y, b = bh >> 3, h = bh & 7;
  const int t = threadIdx.x, w = t >> 6, lane = t & 63;
  const int n = blockIdx.x * 4 + w;
  __shared__ float qs[4][64];
  __shared__ float ps[4][128];
  qs[w][lane] = q[((size_t)b * N_ + n) * D_ + h * 64 + lane];
  __syncthreads();
  const float scale = 0.125f;      // 1/sqrt(64)
  float s0 = 0.f, s1 = 0.f;
  const float* k0p = k + ((size_t)b * P_ + lane) * D_ + h * 64;
  const float* k1p = k0p + (size_t)64 * D_;
#pragma unroll
  for (int d = 0; d < 64; d += 4) {
    float4 a  = *(const float4*)(k0p + d);
    float4 bq = *(const float4*)(k1p + d);
    float q0 = qs[w][d], q1 = qs[w][d + 1], q2 = qs[w][d + 2], q3 = qs[w][d + 3];
    s0 += a.x * q0 + a.y * q1 + a.z * q2 + a.w * q3;
    s1 += bq.x * q0 + bq.y * q1 + bq.z * q2 + bq.w * q3;
  }
  s0 *= scale; s1 *= scale;
  float mx = fmaxf(s0, s1);
#pragma unroll
  for (int off = 32; off >= 1; off >>= 1) mx = fmaxf(mx, __shfl_xor(mx, off));
  float p0 = __expf(s0 - mx), p1 = __expf(s1 - mx);
  float sm = p0 + p1;
#pragma unroll
  for (int off = 32; off >= 1; off >>= 1) sm += __shfl_xor(sm, off);
  ps[w][lane] = p0; ps[w][64 + lane] = p1;
  __syncthreads();
  float acc = 0.f;
  const float* vp = v + ((size_t)b * P_) * D_ + h * 64 + lane;
#pragma unroll 4
  for (int m = 0; m < 128; ++m) acc += ps[w][m] * vp[(size_t)m * D_];
  co[((size_t)b * N_ + n) * D_ + h * 64 + lane] = acc / sm;
}

// ---------------------------------------------------------------------------
// norms of V1 over the c-axis (3), into scaler cols 512..1023
// ---------------------------------------------------------------------------
__global__ __launch_bounds__(256) void vnorm_kernel(
    const float* __restrict__ Vp, float* __restrict__ scal)
{
  size_t i = (size_t)blockIdx.x * 256 + threadIdx.x;   // 0 .. 4096*512
  size_t bn = i >> 9; int d = (int)(i & 511);
  size_t base = bn * 3 * 1024 + d;
  float a = Vp[base], b = Vp[base + 1024], c = Vp[base + 2048];
  scal[bn * 1024 + 512 + d] = sqrtf(a * a + b * b + c * c);
}

// ---------------------------------------------------------------------------
// final: H = so[:,:512] + H2 ; V = so[:,512:][...,None,:] * V2 + Vnew
// ---------------------------------------------------------------------------
__global__ __launch_bounds__(256) void final_kernel(
    const float* __restrict__ so, const float* __restrict__ H2,
    const float* __restrict__ Vp, const float* __restrict__ Vnew,
    float* __restrict__ out)
{
  size_t i = (size_t)blockIdx.x * 256 + threadIdx.x;   // 0 .. 4096*512
  size_t bn = i >> 9; int d = (int)(i & 511);
  out[bn * 512 + d] = so[bn * 1024 + d] + H2[bn * 512 + d];
  float vu = so[bn * 1024 + 512 + d];
  float* outV = out + (size_t)B_ * N_ * D_;
#pragma unroll
  for (int c = 0; c < 3; ++c) {
    size_t vi = (bn * 3 + c) * 512 + d;
    outV[vi] = vu * Vp[(bn * 3 + c) * 1024 + 512 + d] + Vnew[vi];
  }
}

// ---------------------------------------------------------------------------
extern "C" void kernel_launch(void* const* d_in, const int* in_sizes, int n_in,
                              void* d_out, int out_size, void* d_ws, size_t ws_size,
                              hipStream_t stream)
{
  const float* H      = (const float*)d_in[0];
  const float* V      = (const float*)d_in[1];
  const float* Db     = (const float*)d_in[2];
  const float* rbf    = (const float*)d_in[3];
  const float* prompt = (const float*)d_in[4];
  const float* Wq  = (const float*)d_in[5];
  const float* bq  = (const float*)d_in[6];
  const float* Wk  = (const float*)d_in[7];
  const float* bk  = (const float*)d_in[8];
  const float* Wv  = (const float*)d_in[9];
  const float* bv  = (const float*)d_in[10];
  const float* Wvv = (const float*)d_in[11];
  const float* Wo  = (const float*)d_in[12];
  const float* bo  = (const float*)d_in[13];
  const float* Wvo = (const float*)d_in[14];
  const float* ln1g = (const float*)d_in[15];
  const float* ln1b = (const float*)d_in[16];
  const float* caw  = (const float*)d_in[17];
  const float* cab  = (const float*)d_in[18];
  const float* caow = (const float*)d_in[19];
  const float* caob = (const float*)d_in[20];
  const float* casw = (const float*)d_in[21];
  const float* casb = (const float*)d_in[22];
  const float* ln2g = (const float*)d_in[23];
  const float* ln2b = (const float*)d_in[24];
  const float* flv  = (const float*)d_in[25];
  const float* fw1  = (const float*)d_in[26];
  const float* fb1  = (const float*)d_in[27];
  const float* fw2  = (const float*)d_in[28];
  const float* fb2  = (const float*)d_in[29];
  const float* ln3g = (const float*)d_in[30];
  const float* ln3b = (const float*)d_in[31];
  const int*   mask = (const int*)d_in[32];

  float* ws  = (float*)d_ws;
  float* out = (float*)d_out;

  const size_t M1 = (size_t)1 << 20;
  // phase 1
  float* HQ   = ws;              // 8M floats
  float* HK   = ws + 8  * M1;    // 8M
  float* VVT  = ws + 16 * M1;    // 6M
  float* VRES = ws + 22 * M1;    // 6M
  float* HN   = ws + 28 * M1;    // 2M  (-> HRES)
  float* HV   = ws + 30 * M1;    // 2M  (-> H2)
  float* H1   = ws + 32 * M1;    // 2M
  float* VNEW = ws + 34 * M1;    // 6M
  float* HRES = HN;
  // phase 2 aliases
  float* HN2 = ws;               // 2M
  float* QC  = ws + 2 * M1;      // 2M
  float* KC  = ws + 4 * M1;
  float* VC  = ws + 5 * M1;
  float* CO  = ws + 16 * M1;
  float* CO2 = ws + 18 * M1;
  float* H2  = ws + 30 * M1;
  // phase 3 aliases
  float* VP   = ws;              // 12M
  float* SCAL = ws + 12 * M1;    // 4M
  float* HH1  = ws + 16 * M1;    // 8M
  float* SO   = ws + 24 * M1;    // 4M

  // ---- block 1: self attention ----
  ln_kernel<<<4096, 256, 0, stream>>>(H, ln1g, ln1b, HN, 512);
  gemm_kernel<<<dim3(16, 32), 256, 0, stream>>>(HN, Wq, bq, nullptr, HQ, 4096, 2048, 512, 1);
  gemm_kernel<<<dim3(16, 32), 256, 0, stream>>>(HN, Wk, bk, nullptr, HK, 4096, 2048, 512, 1);
  gemm_kernel<<<dim3(4, 32), 256, 0, stream>>>(HN, Wv, bv, nullptr, HV, 4096, 512, 512, 1);
  gemm_kernel<<<dim3(4, 96), 256, 0, stream>>>(V, Wvv, nullptr, nullptr, VVT, 12288, 512, 512, 0);
  attn_self_kernel<<<dim3(128, 32), 256, 0, stream>>>(HQ, HK, HV, VVT, Db, rbf, mask, HRES, VRES);
  gemm_kernel<<<dim3(4, 32), 256, 0, stream>>>(HRES, Wo, bo, H, H1, 4096, 512, 512, 3);
  gemm_kernel<<<dim3(4, 96), 256, 0, stream>>>(VRES, Wvo, nullptr, V, VNEW, 12288, 512, 512, 2);

  // ---- block 2: cross attention ----
  ln_kernel<<<4096, 256, 0, stream>>>(H1, ln2g, ln2b, HN2, 512);
  gemm_kernel<<<dim3(4, 32), 256, 0, stream>>>(HN2, caw, cab, nullptr, QC, 4096, 512, 512, 1);
  gemm_kernel<<<dim3(4, 4), 256, 0, stream>>>(prompt, caw + 262144, cab + 512, nullptr, KC, 512, 512, 512, 1);
  gemm_kernel<<<dim3(4, 4), 256, 0, stream>>>(prompt, caw + 524288, cab + 1024, nullptr, VC, 512, 512, 512, 1);
  attn_cross_kernel<<<dim3(256, 32), 256, 0, stream>>>(QC, KC, VC, CO);
  gemm_kernel<<<dim3(4, 32), 256, 0, stream>>>(CO, caow, caob, nullptr, CO2, 4096, 512, 512, 1);
  gemm_kernel<<<dim3(4, 32), 256, 0, stream>>>(CO2, casw, casb, H1, H2, 4096, 512, 512, 3);

  // ---- block 3: FFN ----
  ln_kernel<<<4096, 256, 0, stream>>>(H2, ln3g, ln3b, SCAL, 1024);
  gemm_kernel<<<dim3(8, 96), 256, 0, stream>>>(VNEW, flv, nullptr, nullptr, VP, 12288, 1024, 512, 0);
  vnorm_kernel<<<8192, 256, 0, stream>>>(VP, SCAL);
  gemm_kernel<<<dim3(16, 32), 256, 0, stream>>>(SCAL, fw1, fb1, nullptr, HH1, 4096, 2048, 1024, 5);
  gemm_kernel<<<dim3(8, 32), 256, 0, stream>>>(HH1, fw2, fb2, nullptr, SO, 4096, 1024, 2048, 1);
  final_kernel<<<8192, 256, 0, stream>>>(SO, H2, VP, VNEW, out);

  (void)in_sizes; (void)n_in; (void)out_size; (void)ws_size;
}

// Round 2
// 823.699 us; speedup vs baseline: 4.4399x; 4.4399x over previous
//
#include <hip/hip_runtime.h>
#include <cstdint>
#include <cstddef>

#define B_    4
#define N_    1024
#define P_    128
#define D_    512
#define NH_   8

typedef unsigned short ushort_t;
typedef short short8 __attribute__((ext_vector_type(8)));
typedef float f32x4 __attribute__((ext_vector_type(4)));

__device__ inline ushort_t f2bf(float f) {
  union { float fp; unsigned int u; } v; v.fp = f;
  unsigned int r = v.u + 0x7fffu + ((v.u >> 16) & 1u);
  return (ushort_t)(r >> 16);
}

// ---------------------------------------------------------------------------
// fp32 -> bf16 cast, 8 elems/thread
// ---------------------------------------------------------------------------
__global__ __launch_bounds__(256) void castk(const float* __restrict__ src,
                                             ushort_t* __restrict__ dst, int n8)
{
  int i = blockIdx.x * 256 + threadIdx.x;
  if (i >= n8) return;
  const float* s = src + (size_t)i * 8;
  short8 o;
#pragma unroll
  for (int j = 0; j < 8; ++j) o[j] = (short)f2bf(s[j]);
  *(short8*)(dst + (size_t)i * 8) = o;
}

// ---------------------------------------------------------------------------
// combined bias: out[b,n,m] = mask[b,m] ? rbf[b,0,n,m]+Db[b,n,m] : -1e30
// ---------------------------------------------------------------------------
__global__ __launch_bounds__(256) void biascomb(const float* __restrict__ Db,
                                                const float* __restrict__ rbf,
                                                const int* __restrict__ mask,
                                                float* __restrict__ out)
{
  size_t i = (size_t)blockIdx.x * 256 + threadIdx.x;
  size_t e = i * 4;
  int b  = (int)(e >> 20);
  int m0 = (int)(e & 1023);
  float4 r = *(const float4*)(rbf + e);
  float4 d = *(const float4*)(Db + e);
  const int* mp = mask + b * 1024 + m0;
  float4 o;
  o.x = mp[0] ? r.x + d.x : -1e30f;
  o.y = mp[1] ? r.y + d.y : -1e30f;
  o.z = mp[2] ? r.z + d.z : -1e30f;
  o.w = mp[3] ? r.w + d.w : -1e30f;
  *(float4*)(out + e) = o;
}

// ---------------------------------------------------------------------------
// LayerNorm (fp32 in, bf16 out), one block per row of 512
// ---------------------------------------------------------------------------
__global__ __launch_bounds__(256) void ln_kernel(
    const float* __restrict__ x, const float* __restrict__ g,
    const float* __restrict__ bb, ushort_t* __restrict__ y, int ostride)
{
  int row = blockIdx.x;
  int t = threadIdx.x;
  const float* xr = x + (size_t)row * D_;
  float a = xr[t], c = xr[t + 256];
  float s = a + c, sq = a * a + c * c;
#pragma unroll
  for (int off = 32; off >= 1; off >>= 1) {
    s  += __shfl_xor(s, off);
    sq += __shfl_xor(sq, off);
  }
  __shared__ float red[8];
  int w = t >> 6, lane = t & 63;
  if (lane == 0) { red[w] = s; red[4 + w] = sq; }
  __syncthreads();
  float st  = red[0] + red[1] + red[2] + red[3];
  float sqt = red[4] + red[5] + red[6] + red[7];
  float mean = st * (1.0f / D_);
  float var  = sqt * (1.0f / D_) - mean * mean;
  float inv  = rsqrtf(var + 1e-5f);
  y[(size_t)row * ostride + t]       = f2bf((a - mean) * inv * g[t] + bb[t]);
  y[(size_t)row * ostride + t + 256] = f2bf((c - mean) * inv * g[t + 256] + bb[t + 256]);
}

// ---------------------------------------------------------------------------
// bf16 MFMA GEMM: C[M,N] = A[M,K] @ W[N,K]^T (+bias)(silu)(+res)
// 128x128 tile, BK=32, 256 thr = 4 waves (2x2), wave = 64x64 via 4x4 frags.
// MFMA layouts (gfx950 16x16x32): A: lane l -> A[l&15][8*(l>>4)+j];
// B: lane l -> B[8*(l>>4)+j][l&15]; D: lane l, reg r -> D[4*(l>>4)+r][l&15].
// flags: 1=bias 2=res 4=silu 8=write fp32 16=write bf16
// ---------------------------------------------------------------------------
__global__ __launch_bounds__(256) void gemm_bf16(
    const ushort_t* __restrict__ A, const ushort_t* __restrict__ W,
    const float* __restrict__ bias, const float* __restrict__ res,
    float* __restrict__ Cf, ushort_t* __restrict__ Cb,
    int M, int N, int K, int flags)
{
  __shared__ __align__(16) ushort_t Al[128][40];
  __shared__ __align__(16) ushort_t Wl[128][40];
  const int t = threadIdx.x;
  const int wv = t >> 6, lane = t & 63, lr = lane & 15, lk = lane >> 4;
  const int wr = wv >> 1, wc = wv & 1;
  const size_t row0 = (size_t)blockIdx.y * 128;
  const size_t col0 = (size_t)blockIdx.x * 128;
  const int srow = t >> 1, scol = (t & 1) * 16;
  const ushort_t* Ap = A + (row0 + srow) * K + scol;
  const ushort_t* Wp = W + (col0 + srow) * K + scol;

  f32x4 acc[4][4];
#pragma unroll
  for (int i = 0; i < 4; ++i)
#pragma unroll
    for (int j = 0; j < 4; ++j) acc[i][j] = f32x4{0.f, 0.f, 0.f, 0.f};

  for (int k0 = 0; k0 < K; k0 += 32) {
    short8 a0 = *(const short8*)(Ap + k0);
    short8 a1 = *(const short8*)(Ap + k0 + 8);
    short8 w0 = *(const short8*)(Wp + k0);
    short8 w1 = *(const short8*)(Wp + k0 + 8);
    __syncthreads();
    *(short8*)&Al[srow][scol]     = a0;
    *(short8*)&Al[srow][scol + 8] = a1;
    *(short8*)&Wl[srow][scol]     = w0;
    *(short8*)&Wl[srow][scol + 8] = w1;
    __syncthreads();
    short8 af[4], bf[4];
#pragma unroll
    for (int i = 0; i < 4; ++i) af[i] = *(const short8*)&Al[wr * 64 + i * 16 + lr][lk * 8];
#pragma unroll
    for (int j = 0; j < 4; ++j) bf[j] = *(const short8*)&Wl[wc * 64 + j * 16 + lr][lk * 8];
#pragma unroll
    for (int i = 0; i < 4; ++i)
#pragma unroll
      for (int j = 0; j < 4; ++j)
        acc[i][j] = __builtin_amdgcn_mfma_f32_16x16x32_bf16(af[i], bf[j], acc[i][j], 0, 0, 0);
  }

  const int orow = wr * 64 + lk * 4, ocol = wc * 64 + lr;
#pragma unroll
  for (int i = 0; i < 4; ++i) {
#pragma unroll
    for (int j = 0; j < 4; ++j) {
      size_t colb = col0 + ocol + j * 16;
      float bv = (flags & 1) ? bias[colb] : 0.f;
#pragma unroll
      for (int r = 0; r < 4; ++r) {
        size_t rowg = row0 + orow + i * 16 + r;
        float v = acc[i][j][r] + bv;
        if (flags & 4) v = v / (1.f + __expf(-v));
        if (flags & 2) v += res[rowg * N + colb];
        if (flags & 8)  Cf[rowg * N + colb] = v;
        if (flags & 16) Cb[rowg * N + colb] = f2bf(v);
      }
    }
  }
}

// ---------------------------------------------------------------------------
// Build VT[b][h][dcat(256)][n(1024)] bf16 from HVb [4096][512] (dcat<64)
// and VVTb [12288][512] (dcat>=64, c=(dcat-64)>>6).  LDS tile transpose.
// ---------------------------------------------------------------------------
__global__ __launch_bounds__(256) void vt_build(
    const ushort_t* __restrict__ HVb, const ushort_t* __restrict__ VVTb,
    ushort_t* __restrict__ VT)
{
  const int bh = blockIdx.z, b = bh >> 3, h = bh & 7;
  const int n0 = blockIdx.x * 64, dt = blockIdx.y;
  __shared__ __align__(16) ushort_t tile[64][72];
  const int t = threadIdx.x;
  {
    int r = t >> 2, c0 = (t & 3) * 16;
    const ushort_t* src = (dt == 0)
      ? HVb + ((size_t)(b * 1024 + n0 + r)) * 512 + h * 64 + c0
      : VVTb + (((size_t)(b * 1024 + n0 + r)) * 3 + (dt - 1)) * 512 + h * 64 + c0;
    *(short8*)&tile[r][c0]     = *(const short8*)src;
    *(short8*)&tile[r][c0 + 8] = *(const short8*)(src + 8);
  }
  __syncthreads();
  {
    int d = t >> 2, nc = (t & 3) * 16;
    short8 o0, o1;
#pragma unroll
    for (int i = 0; i < 8; ++i) { o0[i] = tile[nc + i][d]; o1[i] = tile[nc + 8 + i][d]; }
    ushort_t* dst = VT + ((size_t)bh * 256 + dt * 64 + d) * 1024 + n0 + nc;
    *(short8*)dst = o0;
    *(short8*)(dst + 8) = o1;
  }
}

// ---------------------------------------------------------------------------
// Fused self-attention, bf16 MFMA flash-style.
// Block = (b,h, 64 q-rows), 4 waves, wave owns 16 q-rows x full dcat=256.
// Q in regs (A-frags), K tile in LDS, V^T tile in LDS, P via per-wave LDS.
// ---------------------------------------------------------------------------
__global__ __launch_bounds__(256) void attn_mfma(
    const ushort_t* __restrict__ Qg, const ushort_t* __restrict__ Kg,
    const ushort_t* __restrict__ VTg, const float* __restrict__ biasc,
    ushort_t* __restrict__ HRESb, ushort_t* __restrict__ VRESb)
{
  const int bh = blockIdx.y, b = bh >> 3, h = bh & 7;
  const int q0 = blockIdx.x * 64;
  const int t = threadIdx.x, w = t >> 6, lane = t & 63, lr = lane & 15, lk = lane >> 4;

  __shared__ __align__(16) ushort_t Kl[64][264];
  __shared__ __align__(16) ushort_t Vl[256][72];
  __shared__ __align__(16) ushort_t Pl[4][16][72];

  short8 qf[8];
  {
    const ushort_t* qb = Qg + (((size_t)b * 1024 + q0 + w * 16 + lr) * 8 + h) * 256;
#pragma unroll
    for (int s = 0; s < 8; ++s) qf[s] = *(const short8*)(qb + s * 32 + lk * 8);
  }
  f32x4 o[16];
#pragma unroll
  for (int i = 0; i < 16; ++i) o[i] = f32x4{0.f, 0.f, 0.f, 0.f};
  float mrow[4] = {-1e30f, -1e30f, -1e30f, -1e30f};
  float lsum[4] = {0.f, 0.f, 0.f, 0.f};
  const int qrow_r = q0 + w * 16 + lk * 4;   // + r

  for (int kt = 0; kt < 16; ++kt) {
    const int k0 = kt * 64;
    __syncthreads();
    {
      int key = t >> 2, d0 = (t & 3) * 64;
      const ushort_t* src = Kg + (((size_t)b * 1024 + k0 + key) * 8 + h) * 256 + d0;
#pragma unroll
      for (int c = 0; c < 8; ++c) *(short8*)&Kl[key][d0 + c * 8] = *(const short8*)(src + c * 8);
      const ushort_t* vsrc = VTg + ((size_t)bh * 256 + t) * 1024 + k0;
#pragma unroll
      for (int c = 0; c < 8; ++c) *(short8*)&Vl[t][c * 8] = *(const short8*)(vsrc + c * 8);
    }
    __syncthreads();

    // QK^T: S[16q][64k]
    f32x4 s[4];
#pragma unroll
    for (int j = 0; j < 4; ++j) s[j] = f32x4{0.f, 0.f, 0.f, 0.f};
#pragma unroll
    for (int ks = 0; ks < 8; ++ks) {
#pragma unroll
      for (int j = 0; j < 4; ++j) {
        short8 kf = *(const short8*)&Kl[j * 16 + lr][ks * 32 + lk * 8];
        s[j] = __builtin_amdgcn_mfma_f32_16x16x32_bf16(qf[ks], kf, s[j], 0, 0, 0);
      }
    }
    // scale + bias (D-layout: row = lk*4+r, col = j*16+lr)
    float sv[4][4];
    const float* bp = biasc + ((size_t)b * 1024 + qrow_r) * 1024 + k0 + lr;
#pragma unroll
    for (int r = 0; r < 4; ++r)
#pragma unroll
      for (int j = 0; j < 4; ++j)
        sv[j][r] = s[j][r] * 0.0625f + bp[(size_t)r * 1024 + j * 16];

    // online softmax per q-row (16 lanes share a row; reduce via shfl_xor<16)
    float al[4];
#pragma unroll
    for (int r = 0; r < 4; ++r) {
      float pm = fmaxf(fmaxf(sv[0][r], sv[1][r]), fmaxf(sv[2][r], sv[3][r]));
      pm = fmaxf(pm, __shfl_xor(pm, 1));
      pm = fmaxf(pm, __shfl_xor(pm, 2));
      pm = fmaxf(pm, __shfl_xor(pm, 4));
      pm = fmaxf(pm, __shfl_xor(pm, 8));
      float mn = fmaxf(mrow[r], pm);
      al[r] = __expf(mrow[r] - mn);
      mrow[r] = mn;
      float rs = 0.f;
#pragma unroll
      for (int j = 0; j < 4; ++j) { float p = __expf(sv[j][r] - mn); sv[j][r] = p; rs += p; }
      rs += __shfl_xor(rs, 1); rs += __shfl_xor(rs, 2);
      rs += __shfl_xor(rs, 4); rs += __shfl_xor(rs, 8);
      lsum[r] = lsum[r] * al[r] + rs;
    }
#pragma unroll
    for (int i = 0; i < 16; ++i) {
      o[i][0] *= al[0]; o[i][1] *= al[1]; o[i][2] *= al[2]; o[i][3] *= al[3];
    }
    // P (bf16) to per-wave LDS in A-frag-readable layout
#pragma unroll
    for (int r = 0; r < 4; ++r)
#pragma unroll
      for (int j = 0; j < 4; ++j)
        Pl[w][lk * 4 + r][j * 16 + lr] = f2bf(sv[j][r]);
    __syncthreads();
    // PV: out[16q][256d] += P[16][64] * V[64][256]
#pragma unroll
    for (int ks = 0; ks < 2; ++ks) {
      short8 pf = *(const short8*)&Pl[w][lr][ks * 32 + lk * 8];
#pragma unroll
      for (int d = 0; d < 16; ++d) {
        short8 vf = *(const short8*)&Vl[d * 16 + lr][ks * 32 + lk * 8];
        o[d] = __builtin_amdgcn_mfma_f32_16x16x32_bf16(pf, vf, o[d], 0, 0, 0);
      }
    }
  }

  float inv[4];
#pragma unroll
  for (int r = 0; r < 4; ++r) inv[r] = 1.f / lsum[r];
#pragma unroll
  for (int d = 0; d < 16; ++d) {
    int dcat = d * 16 + lr;
#pragma unroll
    for (int r = 0; r < 4; ++r) {
      float v = o[d][r] * inv[r];
      int n = qrow_r + r;
      if (dcat < 64)
        HRESb[((size_t)b * 1024 + n) * 512 + h * 64 + dcat] = f2bf(v);
      else {
        int c = (dcat - 64) >> 6, jj = (dcat - 64) & 63;
        VRESb[(((size_t)b * 1024 + n) * 3 + c) * 512 + h * 64 + jj] = f2bf(v);
      }
    }
  }
}

// ---------------------------------------------------------------------------
// Cross-attention (fp32, small): one wave per (b,h,n), P=128 keys, DH=64.
// ---------------------------------------------------------------------------
__global__ __launch_bounds__(256) void attn_cross_kernel(
    const float* __restrict__ q, const float* __restrict__ k,
    const float* __restrict__ v, float* __restrict__ co)
{
  const int bh = blockIdx.y, b = bh >> 3, h = bh & 7;
  const int t = threadIdx.x, w = t >> 6, lane = t & 63;
  const int n = blockIdx.x * 4 + w;
  __shared__ float qs[4][64];
  __shared__ float ps[4][128];
  qs[w][lane] = q[((size_t)b * N_ + n) * D_ + h * 64 + lane];
  __syncthreads();
  const float scale = 0.125f;
  float s0 = 0.f, s1 = 0.f;
  const float* k0p = k + ((size_t)b * P_ + lane) * D_ + h * 64;
  const float* k1p = k0p + (size_t)64 * D_;
#pragma unroll
  for (int d = 0; d < 64; d += 4) {
    float4 a  = *(const float4*)(k0p + d);
    float4 bq = *(const float4*)(k1p + d);
    float q0 = qs[w][d], q1 = qs[w][d + 1], q2 = qs[w][d + 2], q3 = qs[w][d + 3];
    s0 += a.x * q0 + a.y * q1 + a.z * q2 + a.w * q3;
    s1 += bq.x * q0 + bq.y * q1 + bq.z * q2 + bq.w * q3;
  }
  s0 *= scale; s1 *= scale;
  float mx = fmaxf(s0, s1);
#pragma unroll
  for (int off = 32; off >= 1; off >>= 1) mx = fmaxf(mx, __shfl_xor(mx, off));
  float p0 = __expf(s0 - mx), p1 = __expf(s1 - mx);
  float sm = p0 + p1;
#pragma unroll
  for (int off = 32; off >= 1; off >>= 1) sm += __shfl_xor(sm, off);
  ps[w][lane] = p0; ps[w][64 + lane] = p1;
  __syncthreads();
  float acc = 0.f;
  const float* vp = v + ((size_t)b * P_) * D_ + h * 64 + lane;
#pragma unroll 4
  for (int m = 0; m < 128; ++m) acc += ps[w][m] * vp[(size_t)m * D_];
  co[((size_t)b * N_ + n) * D_ + h * 64 + lane] = acc / sm;
}

// ---------------------------------------------------------------------------
// norms of V1 over the c-axis (3) -> SCALb cols 512..1023 (bf16)
// ---------------------------------------------------------------------------
__global__ __launch_bounds__(256) void vnorm_kernel(
    const float* __restrict__ Vp, ushort_t* __restrict__ scal)
{
  size_t i = (size_t)blockIdx.x * 256 + threadIdx.x;
  size_t bn = i >> 9; int d = (int)(i & 511);
  size_t base = bn * 3 * 1024 + d;
  float a = Vp[base], b = Vp[base + 1024], c = Vp[base + 2048];
  scal[bn * 1024 + 512 + d] = f2bf(sqrtf(a * a + b * b + c * c));
}

// ---------------------------------------------------------------------------
// final: H = so[:,:512] + H2 ; V = so[:,512:][...,None,:] * V2 + Vnew
// ---------------------------------------------------------------------------
__global__ __launch_bounds__(256) void final_kernel(
    const float* __restrict__ so, const float* __restrict__ H2,
    const float* __restrict__ Vp, const float* __restrict__ Vnew,
    float* __restrict__ out)
{
  size_t i = (size_t)blockIdx.x * 256 + threadIdx.x;
  size_t bn = i >> 9; int d = (int)(i & 511);
  out[bn * 512 + d] = so[bn * 1024 + d] + H2[bn * 512 + d];
  float vu = so[bn * 1024 + 512 + d];
  float* outV = out + (size_t)B_ * N_ * D_;
#pragma unroll
  for (int c = 0; c < 3; ++c) {
    size_t vi = (bn * 3 + c) * 512 + d;
    outV[vi] = vu * Vp[(bn * 3 + c) * 1024 + 512 + d] + Vnew[vi];
  }
}

// ---------------------------------------------------------------------------
extern "C" void kernel_launch(void* const* d_in, const int* in_sizes, int n_in,
                              void* d_out, int out_size, void* d_ws, size_t ws_size,
                              hipStream_t stream)
{
  const float* H      = (const float*)d_in[0];
  const float* V      = (const float*)d_in[1];
  const float* Db     = (const float*)d_in[2];
  const float* rbf    = (const float*)d_in[3];
  const float* prompt = (const float*)d_in[4];
  const float* Wq  = (const float*)d_in[5];
  const float* bq  = (const float*)d_in[6];
  const float* Wk  = (const float*)d_in[7];
  const float* bk  = (const float*)d_in[8];
  const float* Wv  = (const float*)d_in[9];
  const float* bv  = (const float*)d_in[10];
  const float* Wvv = (const float*)d_in[11];
  const float* Wo  = (const float*)d_in[12];
  const float* bo  = (const float*)d_in[13];
  const float* Wvo = (const float*)d_in[14];
  const float* ln1g = (const float*)d_in[15];
  const float* ln1b = (const float*)d_in[16];
  const float* caw  = (const float*)d_in[17];
  const float* cab  = (const float*)d_in[18];
  const float* caow = (const float*)d_in[19];
  const float* caob = (const float*)d_in[20];
  const float* casw = (const float*)d_in[21];
  const float* casb = (const float*)d_in[22];
  const float* ln2g = (const float*)d_in[23];
  const float* ln2b = (const float*)d_in[24];
  const float* flv  = (const float*)d_in[25];
  const float* fw1  = (const float*)d_in[26];
  const float* fb1  = (const float*)d_in[27];
  const float* fw2  = (const float*)d_in[28];
  const float* fb2  = (const float*)d_in[29];
  const float* ln3g = (const float*)d_in[30];
  const float* ln3b = (const float*)d_in[31];
  const int*   mask = (const int*)d_in[32];

  char* wsb = (char*)d_ws;
  float* out = (float*)d_out;

  // offsets in 0.5 MiB units; lifetimes verified phase-by-phase (max 150 MiB)
#define HMB(x) ((size_t)(x) << 19)
  ushort_t* Wqb   = (ushort_t*)(wsb + HMB(0));
  ushort_t* Wkb   = (ushort_t*)(wsb + HMB(4));
  ushort_t* Wvb   = (ushort_t*)(wsb + HMB(8));
  ushort_t* Wvvb  = (ushort_t*)(wsb + HMB(9));
  ushort_t* Wob   = (ushort_t*)(wsb + HMB(10));
  ushort_t* Wvob  = (ushort_t*)(wsb + HMB(11));
  ushort_t* cawb  = (ushort_t*)(wsb + HMB(12));
  ushort_t* caowb = (ushort_t*)(wsb + HMB(15));
  ushort_t* caswb = (ushort_t*)(wsb + HMB(16));
  ushort_t* flvb  = (ushort_t*)(wsb + HMB(17));
  ushort_t* fw1b  = (ushort_t*)(wsb + HMB(19));
  ushort_t* fw2b  = (ushort_t*)(wsb + HMB(27));
  ushort_t* promptb = (ushort_t*)(wsb + HMB(35));
  ushort_t* HQb   = (ushort_t*)(wsb + HMB(36));   // P1-P3
  float*    VNEW  = (float*)   (wsb + HMB(36));   // P4-end
  ushort_t* HKb   = (ushort_t*)(wsb + HMB(84));   // P1-P3
  float*    H2    = (float*)   (wsb + HMB(84));   // P7-end
  float*    KC    = (float*)   (wsb + HMB(100));  // P5-P6
  float*    VC    = (float*)   (wsb + HMB(102));  // P5-P6
  ushort_t* SCALb = (ushort_t*)(wsb + HMB(100));  // P8-P9
  ushort_t* HNb   = (ushort_t*)(wsb + HMB(116));  // P0-P1
  ushort_t* VT    = (ushort_t*)(wsb + HMB(116));  // P2-P3
  float*    QC    = (float*)   (wsb + HMB(116));  // P5-P6
  float*    VP    = (float*)   (wsb + HMB(116));  // P8-end
  float*    CO    = (float*)   (wsb + HMB(132));  // P6
  float*    BIASC = (float*)   (wsb + HMB(148));  // P0-P3
  ushort_t* COb   = (ushort_t*)(wsb + HMB(148));  // P6-P7
  ushort_t* CO2b  = (ushort_t*)(wsb + HMB(156));  // P7
  ushort_t* HN2b  = (ushort_t*)(wsb + HMB(164));  // P5
  ushort_t* Vb    = (ushort_t*)(wsb + HMB(180));  // P0-P1
  ushort_t* HRESb = (ushort_t*)(wsb + HMB(180));  // P3-P4
  ushort_t* VRESb = (ushort_t*)(wsb + HMB(188));  // P3-P4
  ushort_t* VVTb  = (ushort_t*)(wsb + HMB(212));  // P1-P2
  float*    H1    = (float*)   (wsb + HMB(212));  // P4-P7
  ushort_t* HH1b  = (ushort_t*)(wsb + HMB(212));  // P9
  ushort_t* HVb   = (ushort_t*)(wsb + HMB(236));  // P1-P2
  float*    SO    = (float*)   (wsb + HMB(244));  // P9-end
  ushort_t* VNEWb = (ushort_t*)(wsb + HMB(276));  // P4-P8

  auto cast = [&](const float* s, ushort_t* d, size_t n) {
    castk<<<(int)((n / 8 + 255) / 256), 256, 0, stream>>>(s, d, (int)(n / 8));
  };

  // ---- P0: casts + combined bias + ln1 ----
  cast(Wq, Wqb, 2048 * 512);   cast(Wk, Wkb, 2048 * 512);
  cast(Wv, Wvb, 512 * 512);    cast(Wvv, Wvvb, 512 * 512);
  cast(Wo, Wob, 512 * 512);    cast(Wvo, Wvob, 512 * 512);
  cast(caw, cawb, 1536 * 512); cast(caow, caowb, 512 * 512);
  cast(casw, caswb, 512 * 512);cast(flv, flvb, 1024 * 512);
  cast(fw1, fw1b, 2048 * 1024);cast(fw2, fw2b, 1024 * 2048);
  cast(prompt, promptb, 512 * 512);
  cast(V, Vb, (size_t)12288 * 512);
  biascomb<<<4096, 256, 0, stream>>>(Db, rbf, mask, BIASC);
  ln_kernel<<<4096, 256, 0, stream>>>(H, ln1g, ln1b, HNb, 512);

  // ---- P1: QKV + Vv projections ----
  gemm_bf16<<<dim3(16, 32), 256, 0, stream>>>(HNb, Wqb, bq, nullptr, nullptr, HQb, 4096, 2048, 512, 1 | 16);
  gemm_bf16<<<dim3(16, 32), 256, 0, stream>>>(HNb, Wkb, bk, nullptr, nullptr, HKb, 4096, 2048, 512, 1 | 16);
  gemm_bf16<<<dim3(4, 32), 256, 0, stream>>>(HNb, Wvb, bv, nullptr, nullptr, HVb, 4096, 512, 512, 1 | 16);
  gemm_bf16<<<dim3(4, 96), 256, 0, stream>>>(Vb, Wvvb, nullptr, nullptr, nullptr, VVTb, 12288, 512, 512, 16);

  // ---- P2: V^T layout build ----
  vt_build<<<dim3(16, 4, 32), 256, 0, stream>>>(HVb, VVTb, VT);

  // ---- P3: fused self-attention ----
  attn_mfma<<<dim3(16, 32), 256, 0, stream>>>(HQb, HKb, VT, BIASC, HRESb, VRESb);

  // ---- P4: output projections + residuals ----
  gemm_bf16<<<dim3(4, 32), 256, 0, stream>>>(HRESb, Wob, bo, H, H1, nullptr, 4096, 512, 512, 1 | 2 | 8);
  gemm_bf16<<<dim3(4, 96), 256, 0, stream>>>(VRESb, Wvob, nullptr, V, VNEW, VNEWb, 12288, 512, 512, 2 | 8 | 16);

  // ---- P5: cross-attention projections ----
  ln_kernel<<<4096, 256, 0, stream>>>(H1, ln2g, ln2b, HN2b, 512);
  gemm_bf16<<<dim3(4, 32), 256, 0, stream>>>(HN2b, cawb, cab, nullptr, QC, nullptr, 4096, 512, 512, 1 | 8);
  gemm_bf16<<<dim3(4, 4), 256, 0, stream>>>(promptb, cawb + 262144, cab + 512, nullptr, KC, nullptr, 512, 512, 512, 1 | 8);
  gemm_bf16<<<dim3(4, 4), 256, 0, stream>>>(promptb, cawb + 524288, cab + 1024, nullptr, VC, nullptr, 512, 512, 512, 1 | 8);

  // ---- P6: cross-attention ----
  attn_cross_kernel<<<dim3(256, 32), 256, 0, stream>>>(QC, KC, VC, CO);
  cast(CO, COb, (size_t)4096 * 512);

  // ---- P7: cross-attention output path ----
  gemm_bf16<<<dim3(4, 32), 256, 0, stream>>>(COb, caowb, caob, nullptr, nullptr, CO2b, 4096, 512, 512, 1 | 16);
  gemm_bf16<<<dim3(4, 32), 256, 0, stream>>>(CO2b, caswb, casb, H1, H2, nullptr, 4096, 512, 512, 1 | 2 | 8);

  // ---- P8: FFN inputs ----
  gemm_bf16<<<dim3(8, 96), 256, 0, stream>>>(VNEWb, flvb, nullptr, nullptr, VP, nullptr, 12288, 1024, 512, 8);
  ln_kernel<<<4096, 256, 0, stream>>>(H2, ln3g, ln3b, SCALb, 1024);
  vnorm_kernel<<<8192, 256, 0, stream>>>(VP, SCALb);

  // ---- P9: FFN ----
  gemm_bf16<<<dim3(16, 32), 256, 0, stream>>>(SCALb, fw1b, fb1, nullptr, nullptr, HH1b, 4096, 2048, 1024, 1 | 4 | 16);
  gemm_bf16<<<dim3(8, 32), 256, 0, stream>>>(HH1b, fw2b, fb2, nullptr, SO, nullptr, 4096, 1024, 2048, 1 | 8);

  // ---- P10: final combine ----
  final_kernel<<<8192, 256, 0, stream>>>(SO, H2, VP, VNEW, out);

  (void)in_sizes; (void)n_in; (void)out_size; (void)ws_size; (void)prompt;
}

// Round 3
// 653.779 us; speedup vs baseline: 5.5939x; 1.2599x over previous
//
#include <hip/hip_runtime.h>
#include <cstdint>
#include <cstddef>

#define B_    4
#define N_    1024
#define P_    128
#define D_    512
#define NH_   8

typedef unsigned short ushort_t;
typedef short short8 __attribute__((ext_vector_type(8)));
typedef float f32x4 __attribute__((ext_vector_type(4)));
typedef ushort_t ushort4_t __attribute__((ext_vector_type(4)));

__device__ inline ushort_t f2bf(float f) {
  union { float fp; unsigned int u; } v; v.fp = f;
  unsigned int r = v.u + 0x7fffu + ((v.u >> 16) & 1u);
  return (ushort_t)(r >> 16);
}
__device__ inline float bf2f(ushort_t u) {
  union { unsigned int i; float f; } v; v.i = ((unsigned int)u) << 16;
  return v.f;
}

// ---------------------------------------------------------------------------
// fp32 -> bf16 cast, 8 elems/thread
// ---------------------------------------------------------------------------
__global__ __launch_bounds__(256) void castk(const float* __restrict__ src,
                                             ushort_t* __restrict__ dst, int n8)
{
  int i = blockIdx.x * 256 + threadIdx.x;
  if (i >= n8) return;
  const float* s = src + (size_t)i * 8;
  short8 o;
#pragma unroll
  for (int j = 0; j < 8; ++j) o[j] = (short)f2bf(s[j]);
  *(short8*)(dst + (size_t)i * 8) = o;
}

// ---------------------------------------------------------------------------
// combined bias (bf16): out[b,n,m] = mask[b,m] ? rbf[b,0,n,m]+Db[b,n,m] : -1e30
// ---------------------------------------------------------------------------
__global__ __launch_bounds__(256) void biascomb(const float* __restrict__ Db,
                                                const float* __restrict__ rbf,
                                                const int* __restrict__ mask,
                                                ushort_t* __restrict__ out)
{
  size_t i = (size_t)blockIdx.x * 256 + threadIdx.x;
  size_t e = i * 4;
  int b  = (int)(e >> 20);
  int m0 = (int)(e & 1023);
  float4 r = *(const float4*)(rbf + e);
  float4 d = *(const float4*)(Db + e);
  const int* mp = mask + b * 1024 + m0;
  ushort4_t o;
  o.x = f2bf(mp[0] ? r.x + d.x : -1e30f);
  o.y = f2bf(mp[1] ? r.y + d.y : -1e30f);
  o.z = f2bf(mp[2] ? r.z + d.z : -1e30f);
  o.w = f2bf(mp[3] ? r.w + d.w : -1e30f);
  *(ushort4_t*)(out + e) = o;
}

// ---------------------------------------------------------------------------
// LayerNorm (fp32 in, bf16 out), one block per row of 512
// ---------------------------------------------------------------------------
__global__ __launch_bounds__(256) void ln_kernel(
    const float* __restrict__ x, const float* __restrict__ g,
    const float* __restrict__ bb, ushort_t* __restrict__ y, int ostride)
{
  int row = blockIdx.x;
  int t = threadIdx.x;
  const float* xr = x + (size_t)row * D_;
  float a = xr[t], c = xr[t + 256];
  float s = a + c, sq = a * a + c * c;
#pragma unroll
  for (int off = 32; off >= 1; off >>= 1) {
    s  += __shfl_xor(s, off);
    sq += __shfl_xor(sq, off);
  }
  __shared__ float red[8];
  int w = t >> 6, lane = t & 63;
  if (lane == 0) { red[w] = s; red[4 + w] = sq; }
  __syncthreads();
  float st  = red[0] + red[1] + red[2] + red[3];
  float sqt = red[4] + red[5] + red[6] + red[7];
  float mean = st * (1.0f / D_);
  float var  = sqt * (1.0f / D_) - mean * mean;
  float inv  = rsqrtf(var + 1e-5f);
  y[(size_t)row * ostride + t]       = f2bf((a - mean) * inv * g[t] + bb[t]);
  y[(size_t)row * ostride + t + 256] = f2bf((c - mean) * inv * g[t + 256] + bb[t + 256]);
}

// ---------------------------------------------------------------------------
// bf16 MFMA GEMM: C[M,N] = A[M,K] @ W[N,K]^T (+bias)(silu)(+res)
// 128x128 tile, BK=32, 256 thr = 4 waves (2x2), wave = 64x64 via 4x4 frags.
// flags: 1=bias 2=res 4=silu 8=write fp32 16=write bf16
// ---------------------------------------------------------------------------
__global__ __launch_bounds__(256) void gemm_bf16(
    const ushort_t* __restrict__ A, const ushort_t* __restrict__ W,
    const float* __restrict__ bias, const float* __restrict__ res,
    float* __restrict__ Cf, ushort_t* __restrict__ Cb,
    int M, int N, int K, int flags)
{
  __shared__ __align__(16) ushort_t Al[128][40];
  __shared__ __align__(16) ushort_t Wl[128][40];
  const int t = threadIdx.x;
  const int wv = t >> 6, lane = t & 63, lr = lane & 15, lk = lane >> 4;
  const int wr = wv >> 1, wc = wv & 1;
  const size_t row0 = (size_t)blockIdx.y * 128;
  const size_t col0 = (size_t)blockIdx.x * 128;
  const int srow = t >> 1, scol = (t & 1) * 16;
  const ushort_t* Ap = A + (row0 + srow) * K + scol;
  const ushort_t* Wp = W + (col0 + srow) * K + scol;

  f32x4 acc[4][4];
#pragma unroll
  for (int i = 0; i < 4; ++i)
#pragma unroll
    for (int j = 0; j < 4; ++j) acc[i][j] = f32x4{0.f, 0.f, 0.f, 0.f};

  for (int k0 = 0; k0 < K; k0 += 32) {
    short8 a0 = *(const short8*)(Ap + k0);
    short8 a1 = *(const short8*)(Ap + k0 + 8);
    short8 w0 = *(const short8*)(Wp + k0);
    short8 w1 = *(const short8*)(Wp + k0 + 8);
    __syncthreads();
    *(short8*)&Al[srow][scol]     = a0;
    *(short8*)&Al[srow][scol + 8] = a1;
    *(short8*)&Wl[srow][scol]     = w0;
    *(short8*)&Wl[srow][scol + 8] = w1;
    __syncthreads();
    short8 af[4], bf[4];
#pragma unroll
    for (int i = 0; i < 4; ++i) af[i] = *(const short8*)&Al[wr * 64 + i * 16 + lr][lk * 8];
#pragma unroll
    for (int j = 0; j < 4; ++j) bf[j] = *(const short8*)&Wl[wc * 64 + j * 16 + lr][lk * 8];
#pragma unroll
    for (int i = 0; i < 4; ++i)
#pragma unroll
      for (int j = 0; j < 4; ++j)
        acc[i][j] = __builtin_amdgcn_mfma_f32_16x16x32_bf16(af[i], bf[j], acc[i][j], 0, 0, 0);
  }

  const int orow = wr * 64 + lk * 4, ocol = wc * 64 + lr;
#pragma unroll
  for (int i = 0; i < 4; ++i) {
#pragma unroll
    for (int j = 0; j < 4; ++j) {
      size_t colb = col0 + ocol + j * 16;
      float bv = (flags & 1) ? bias[colb] : 0.f;
#pragma unroll
      for (int r = 0; r < 4; ++r) {
        size_t rowg = row0 + orow + i * 16 + r;
        float v = acc[i][j][r] + bv;
        if (flags & 4) v = v / (1.f + __expf(-v));
        if (flags & 2) v += res[rowg * N + colb];
        if (flags & 8)  Cf[rowg * N + colb] = v;
        if (flags & 16) Cb[rowg * N + colb] = f2bf(v);
      }
    }
  }
}

// ---------------------------------------------------------------------------
// Build VT[b][h][dcat(256)][n(1024)] bf16 from HVb [4096][512] (dcat<64)
// and VVTb [12288][512] (dcat>=64, c=(dcat-64)>>6).  LDS tile transpose.
// ---------------------------------------------------------------------------
__global__ __launch_bounds__(256) void vt_build(
    const ushort_t* __restrict__ HVb, const ushort_t* __restrict__ VVTb,
    ushort_t* __restrict__ VT)
{
  const int bh = blockIdx.z, b = bh >> 3, h = bh & 7;
  const int n0 = blockIdx.x * 64, dt = blockIdx.y;
  __shared__ __align__(16) ushort_t tile[64][72];
  const int t = threadIdx.x;
  {
    int r = t >> 2, c0 = (t & 3) * 16;
    const ushort_t* src = (dt == 0)
      ? HVb + ((size_t)(b * 1024 + n0 + r)) * 512 + h * 64 + c0
      : VVTb + (((size_t)(b * 1024 + n0 + r)) * 3 + (dt - 1)) * 512 + h * 64 + c0;
    *(short8*)&tile[r][c0]     = *(const short8*)src;
    *(short8*)&tile[r][c0 + 8] = *(const short8*)(src + 8);
  }
  __syncthreads();
  {
    int d = t >> 2, nc = (t & 3) * 16;
    short8 o0, o1;
#pragma unroll
    for (int i = 0; i < 8; ++i) { o0[i] = tile[nc + i][d]; o1[i] = tile[nc + 8 + i][d]; }
    ushort_t* dst = VT + ((size_t)bh * 256 + dt * 64 + d) * 1024 + n0 + nc;
    *(short8*)dst = o0;
    *(short8*)(dst + 8) = o1;
  }
}

// ---------------------------------------------------------------------------
// Fused self-attention, bf16 MFMA flash-style.
// Block = (b,h, 64 q-rows), 4 waves, wave owns 16 q-rows x full dcat=256.
// ---------------------------------------------------------------------------
__global__ __launch_bounds__(256) void attn_mfma(
    const ushort_t* __restrict__ Qg, const ushort_t* __restrict__ Kg,
    const ushort_t* __restrict__ VTg, const ushort_t* __restrict__ biasb,
    ushort_t* __restrict__ HRESb, ushort_t* __restrict__ VRESb)
{
  const int bh = blockIdx.y, b = bh >> 3, h = bh & 7;
  const int q0 = blockIdx.x * 64;
  const int t = threadIdx.x, w = t >> 6, lane = t & 63, lr = lane & 15, lk = lane >> 4;

  __shared__ __align__(16) ushort_t Kl[64][264];
  __shared__ __align__(16) ushort_t Vl[256][72];
  __shared__ __align__(16) ushort_t Pl[4][16][72];

  short8 qf[8];
  {
    const ushort_t* qb = Qg + (((size_t)b * 1024 + q0 + w * 16 + lr) * 8 + h) * 256;
#pragma unroll
    for (int s = 0; s < 8; ++s) qf[s] = *(const short8*)(qb + s * 32 + lk * 8);
  }
  f32x4 o[16];
#pragma unroll
  for (int i = 0; i < 16; ++i) o[i] = f32x4{0.f, 0.f, 0.f, 0.f};
  float mrow[4] = {-1e30f, -1e30f, -1e30f, -1e30f};
  float lsum[4] = {0.f, 0.f, 0.f, 0.f};
  const int qrow_r = q0 + w * 16 + lk * 4;   // + r

  for (int kt = 0; kt < 16; ++kt) {
    const int k0 = kt * 64;
    __syncthreads();
    {
      int key = t >> 2, d0 = (t & 3) * 64;
      const ushort_t* src = Kg + (((size_t)b * 1024 + k0 + key) * 8 + h) * 256 + d0;
#pragma unroll
      for (int c = 0; c < 8; ++c) *(short8*)&Kl[key][d0 + c * 8] = *(const short8*)(src + c * 8);
      const ushort_t* vsrc = VTg + ((size_t)bh * 256 + t) * 1024 + k0;
#pragma unroll
      for (int c = 0; c < 8; ++c) *(short8*)&Vl[t][c * 8] = *(const short8*)(vsrc + c * 8);
    }
    __syncthreads();

    // QK^T: S[16q][64k]
    f32x4 s[4];
#pragma unroll
    for (int j = 0; j < 4; ++j) s[j] = f32x4{0.f, 0.f, 0.f, 0.f};
#pragma unroll
    for (int ks = 0; ks < 8; ++ks) {
#pragma unroll
      for (int j = 0; j < 4; ++j) {
        short8 kf = *(const short8*)&Kl[j * 16 + lr][ks * 32 + lk * 8];
        s[j] = __builtin_amdgcn_mfma_f32_16x16x32_bf16(qf[ks], kf, s[j], 0, 0, 0);
      }
    }
    // scale + bias (D-layout: row = lk*4+r, col = j*16+lr), bias bf16
    float sv[4][4];
    const ushort_t* bp = biasb + ((size_t)b << 20) + (size_t)qrow_r * 1024 + k0 + lr;
#pragma unroll
    for (int r = 0; r < 4; ++r)
#pragma unroll
      for (int j = 0; j < 4; ++j)
        sv[j][r] = s[j][r] * 0.0625f + bf2f(bp[(size_t)r * 1024 + j * 16]);

    // online softmax per q-row
    float al[4];
#pragma unroll
    for (int r = 0; r < 4; ++r) {
      float pm = fmaxf(fmaxf(sv[0][r], sv[1][r]), fmaxf(sv[2][r], sv[3][r]));
      pm = fmaxf(pm, __shfl_xor(pm, 1));
      pm = fmaxf(pm, __shfl_xor(pm, 2));
      pm = fmaxf(pm, __shfl_xor(pm, 4));
      pm = fmaxf(pm, __shfl_xor(pm, 8));
      float mn = fmaxf(mrow[r], pm);
      al[r] = __expf(mrow[r] - mn);
      mrow[r] = mn;
      float rs = 0.f;
#pragma unroll
      for (int j = 0; j < 4; ++j) { float p = __expf(sv[j][r] - mn); sv[j][r] = p; rs += p; }
      rs += __shfl_xor(rs, 1); rs += __shfl_xor(rs, 2);
      rs += __shfl_xor(rs, 4); rs += __shfl_xor(rs, 8);
      lsum[r] = lsum[r] * al[r] + rs;
    }
#pragma unroll
    for (int i = 0; i < 16; ++i) {
      o[i][0] *= al[0]; o[i][1] *= al[1]; o[i][2] *= al[2]; o[i][3] *= al[3];
    }
#pragma unroll
    for (int r = 0; r < 4; ++r)
#pragma unroll
      for (int j = 0; j < 4; ++j)
        Pl[w][lk * 4 + r][j * 16 + lr] = f2bf(sv[j][r]);
    __syncthreads();
    // PV: out[16q][256d] += P[16][64] * V[64][256]
#pragma unroll
    for (int ks = 0; ks < 2; ++ks) {
      short8 pf = *(const short8*)&Pl[w][lr][ks * 32 + lk * 8];
#pragma unroll
      for (int d = 0; d < 16; ++d) {
        short8 vf = *(const short8*)&Vl[d * 16 + lr][ks * 32 + lk * 8];
        o[d] = __builtin_amdgcn_mfma_f32_16x16x32_bf16(pf, vf, o[d], 0, 0, 0);
      }
    }
  }

  float inv[4];
#pragma unroll
  for (int r = 0; r < 4; ++r) inv[r] = 1.f / lsum[r];
#pragma unroll
  for (int d = 0; d < 16; ++d) {
    int dcat = d * 16 + lr;
#pragma unroll
    for (int r = 0; r < 4; ++r) {
      float v = o[d][r] * inv[r];
      int n = qrow_r + r;
      if (dcat < 64)
        HRESb[((size_t)b * 1024 + n) * 512 + h * 64 + dcat] = f2bf(v);
      else {
        int c = (dcat - 64) >> 6, jj = (dcat - 64) & 63;
        VRESb[(((size_t)b * 1024 + n) * 3 + c) * 512 + h * 64 + jj] = f2bf(v);
      }
    }
  }
}

// ---------------------------------------------------------------------------
// Cross-attention, bf16 MFMA.  Block = (b,h, 64 q-rows), 4 waves x 16 q.
// K [128x64] + V^T [64x128] staged in LDS; single-tile softmax (no online).
// Qb: [4096][512] bf16 (col = h*64+d); KVb: [512][1024] bf16 (K cols 0..511,
// V cols 512..1023, col = h*64+d within each); out COb [4096][512] bf16.
// ---------------------------------------------------------------------------
__global__ __launch_bounds__(256) void attn_cross_mfma(
    const ushort_t* __restrict__ Qb, const ushort_t* __restrict__ KVb,
    ushort_t* __restrict__ COb)
{
  const int bh = blockIdx.y, b = bh >> 3, h = bh & 7;
  const int q0 = blockIdx.x * 64;
  const int t = threadIdx.x, w = t >> 6, lane = t & 63, lr = lane & 15, lk = lane >> 4;

  __shared__ __align__(16) ushort_t Kl[128][72];
  __shared__ __align__(16) ushort_t Vt[64][136];
  __shared__ __align__(16) ushort_t Pl[4][16][136];

  {
    int p = t >> 1, c0 = (t & 1) * 32;
    const ushort_t* kp = KVb + ((size_t)b * 128 + p) * 1024 + h * 64 + c0;
#pragma unroll
    for (int i = 0; i < 4; ++i) {
      short8 kv = *(const short8*)(kp + i * 8);
      *(short8*)&Kl[p][c0 + i * 8] = kv;
      short8 vv = *(const short8*)(kp + 512 + i * 8);
#pragma unroll
      for (int jj = 0; jj < 8; ++jj) Vt[c0 + i * 8 + jj][p] = (ushort_t)vv[jj];
    }
  }
  __syncthreads();

  short8 qf[2];
  {
    const ushort_t* qp = Qb + ((size_t)b * 1024 + q0 + w * 16 + lr) * 512 + h * 64;
    qf[0] = *(const short8*)(qp + lk * 8);
    qf[1] = *(const short8*)(qp + 32 + lk * 8);
  }

  // scores S[16q][128k]
  f32x4 s[8];
#pragma unroll
  for (int j = 0; j < 8; ++j) s[j] = f32x4{0.f, 0.f, 0.f, 0.f};
#pragma unroll
  for (int ks = 0; ks < 2; ++ks)
#pragma unroll
    for (int j = 0; j < 8; ++j) {
      short8 kf = *(const short8*)&Kl[j * 16 + lr][ks * 32 + lk * 8];
      s[j] = __builtin_amdgcn_mfma_f32_16x16x32_bf16(qf[ks], kf, s[j], 0, 0, 0);
    }

  // softmax rows (row = lk*4+r), cols j*16+lr; reduce over 16-lane group
  float linv[4];
#pragma unroll
  for (int r = 0; r < 4; ++r) {
    float sc[8];
#pragma unroll
    for (int j = 0; j < 8; ++j) sc[j] = s[j][r] * 0.125f;
    float mx = sc[0];
#pragma unroll
    for (int j = 1; j < 8; ++j) mx = fmaxf(mx, sc[j]);
    mx = fmaxf(mx, __shfl_xor(mx, 1));
    mx = fmaxf(mx, __shfl_xor(mx, 2));
    mx = fmaxf(mx, __shfl_xor(mx, 4));
    mx = fmaxf(mx, __shfl_xor(mx, 8));
    float rs = 0.f;
#pragma unroll
    for (int j = 0; j < 8; ++j) {
      float p = __expf(sc[j] - mx);
      rs += p;
      Pl[w][lk * 4 + r][j * 16 + lr] = f2bf(p);
    }
    rs += __shfl_xor(rs, 1); rs += __shfl_xor(rs, 2);
    rs += __shfl_xor(rs, 4); rs += __shfl_xor(rs, 8);
    linv[r] = 1.f / rs;
  }
  __syncthreads();

  // PV: out[16q][64d] = P[16][128] * V[128][64]
  f32x4 o[4];
#pragma unroll
  for (int d = 0; d < 4; ++d) o[d] = f32x4{0.f, 0.f, 0.f, 0.f};
#pragma unroll
  for (int ks = 0; ks < 4; ++ks) {
    short8 pf = *(const short8*)&Pl[w][lr][ks * 32 + lk * 8];
#pragma unroll
    for (int d = 0; d < 4; ++d) {
      short8 vf = *(const short8*)&Vt[d * 16 + lr][ks * 32 + lk * 8];
      o[d] = __builtin_amdgcn_mfma_f32_16x16x32_bf16(pf, vf, o[d], 0, 0, 0);
    }
  }

#pragma unroll
  for (int d = 0; d < 4; ++d)
#pragma unroll
    for (int r = 0; r < 4; ++r) {
      int n = q0 + w * 16 + lk * 4 + r;
      COb[((size_t)b * 1024 + n) * 512 + h * 64 + d * 16 + lr] = f2bf(o[d][r] * linv[r]);
    }
}

// ---------------------------------------------------------------------------
// norms of V1 over the c-axis (3) -> SCALb cols 512..1023 (bf16)
// ---------------------------------------------------------------------------
__global__ __launch_bounds__(256) void vnorm_kernel(
    const float* __restrict__ Vp, ushort_t* __restrict__ scal)
{
  size_t i = (size_t)blockIdx.x * 256 + threadIdx.x;
  size_t bn = i >> 9; int d = (int)(i & 511);
  size_t base = bn * 3 * 1024 + d;
  float a = Vp[base], b = Vp[base + 1024], c = Vp[base + 2048];
  scal[bn * 1024 + 512 + d] = f2bf(sqrtf(a * a + b * b + c * c));
}

// ---------------------------------------------------------------------------
// final: H = so[:,:512] + H2 ; V = so[:,512:][...,None,:] * V2 + Vnew
// ---------------------------------------------------------------------------
__global__ __launch_bounds__(256) void final_kernel(
    const float* __restrict__ so, const float* __restrict__ H2,
    const float* __restrict__ Vp, const float* __restrict__ Vnew,
    float* __restrict__ out)
{
  size_t i = (size_t)blockIdx.x * 256 + threadIdx.x;
  size_t bn = i >> 9; int d = (int)(i & 511);
  out[bn * 512 + d] = so[bn * 1024 + d] + H2[bn * 512 + d];
  float vu = so[bn * 1024 + 512 + d];
  float* outV = out + (size_t)B_ * N_ * D_;
#pragma unroll
  for (int c = 0; c < 3; ++c) {
    size_t vi = (bn * 3 + c) * 512 + d;
    outV[vi] = vu * Vp[(bn * 3 + c) * 1024 + 512 + d] + Vnew[vi];
  }
}

// ---------------------------------------------------------------------------
extern "C" void kernel_launch(void* const* d_in, const int* in_sizes, int n_in,
                              void* d_out, int out_size, void* d_ws, size_t ws_size,
                              hipStream_t stream)
{
  const float* H      = (const float*)d_in[0];
  const float* V      = (const float*)d_in[1];
  const float* Db     = (const float*)d_in[2];
  const float* rbf    = (const float*)d_in[3];
  const float* prompt = (const float*)d_in[4];
  const float* Wq  = (const float*)d_in[5];
  const float* bq  = (const float*)d_in[6];
  const float* Wk  = (const float*)d_in[7];
  const float* bk  = (const float*)d_in[8];
  const float* Wv  = (const float*)d_in[9];
  const float* bv  = (const float*)d_in[10];
  const float* Wvv = (const float*)d_in[11];
  const float* Wo  = (const float*)d_in[12];
  const float* bo  = (const float*)d_in[13];
  const float* Wvo = (const float*)d_in[14];
  const float* ln1g = (const float*)d_in[15];
  const float* ln1b = (const float*)d_in[16];
  const float* caw  = (const float*)d_in[17];
  const float* cab  = (const float*)d_in[18];
  const float* caow = (const float*)d_in[19];
  const float* caob = (const float*)d_in[20];
  const float* casw = (const float*)d_in[21];
  const float* casb = (const float*)d_in[22];
  const float* ln2g = (const float*)d_in[23];
  const float* ln2b = (const float*)d_in[24];
  const float* flv  = (const float*)d_in[25];
  const float* fw1  = (const float*)d_in[26];
  const float* fb1  = (const float*)d_in[27];
  const float* fw2  = (const float*)d_in[28];
  const float* fb2  = (const float*)d_in[29];
  const float* ln3g = (const float*)d_in[30];
  const float* ln3b = (const float*)d_in[31];
  const int*   mask = (const int*)d_in[32];

  char* wsb = (char*)d_ws;
  float* out = (float*)d_out;

  // offsets in 0.5 MiB units; lifetimes verified phase-by-phase
#define HMB(x) ((size_t)(x) << 19)
  ushort_t* Wqb   = (ushort_t*)(wsb + HMB(0));
  ushort_t* Wkb   = (ushort_t*)(wsb + HMB(4));
  ushort_t* Wvb   = (ushort_t*)(wsb + HMB(8));
  ushort_t* Wvvb  = (ushort_t*)(wsb + HMB(9));
  ushort_t* Wob   = (ushort_t*)(wsb + HMB(10));
  ushort_t* Wvob  = (ushort_t*)(wsb + HMB(11));
  ushort_t* cawb  = (ushort_t*)(wsb + HMB(12));
  ushort_t* caowb = (ushort_t*)(wsb + HMB(15));
  ushort_t* caswb = (ushort_t*)(wsb + HMB(16));
  ushort_t* flvb  = (ushort_t*)(wsb + HMB(17));
  ushort_t* fw1b  = (ushort_t*)(wsb + HMB(19));
  ushort_t* fw2b  = (ushort_t*)(wsb + HMB(27));
  ushort_t* promptb = (ushort_t*)(wsb + HMB(35));
  ushort_t* HQb   = (ushort_t*)(wsb + HMB(36));   // P1-P3
  float*    VNEW  = (float*)   (wsb + HMB(36));   // P4-end
  ushort_t* HKb   = (ushort_t*)(wsb + HMB(84));   // P1-P3
  float*    H2    = (float*)   (wsb + HMB(84));   // P7-end
  ushort_t* KVCb  = (ushort_t*)(wsb + HMB(100));  // P5-P6 (1 MB)
  ushort_t* SCALb = (ushort_t*)(wsb + HMB(100));  // P8-P9
  ushort_t* HNb   = (ushort_t*)(wsb + HMB(116));  // P0-P1
  ushort_t* VT    = (ushort_t*)(wsb + HMB(116));  // P2-P3
  ushort_t* QCb   = (ushort_t*)(wsb + HMB(116));  // P5-P6
  float*    VP    = (float*)   (wsb + HMB(116));  // P8-end
  ushort_t* BIASCb= (ushort_t*)(wsb + HMB(148));  // P0-P3 (8.4 MB)
  ushort_t* COb   = (ushort_t*)(wsb + HMB(148));  // P6-P7
  ushort_t* CO2b  = (ushort_t*)(wsb + HMB(156));  // P7
  ushort_t* HN2b  = (ushort_t*)(wsb + HMB(164));  // P5
  ushort_t* Vb    = (ushort_t*)(wsb + HMB(180));  // P0-P1
  ushort_t* HRESb = (ushort_t*)(wsb + HMB(180));  // P3-P4
  ushort_t* VRESb = (ushort_t*)(wsb + HMB(188));  // P3-P4
  ushort_t* VVTb  = (ushort_t*)(wsb + HMB(212));  // P1-P2
  float*    H1    = (float*)   (wsb + HMB(212));  // P4-P7
  ushort_t* HH1b  = (ushort_t*)(wsb + HMB(212));  // P9
  ushort_t* HVb   = (ushort_t*)(wsb + HMB(236));  // P1-P2
  float*    SO    = (float*)   (wsb + HMB(244));  // P9-end
  ushort_t* VNEWb = (ushort_t*)(wsb + HMB(276));  // P4-P8

  auto cast = [&](const float* s, ushort_t* d, size_t n) {
    castk<<<(int)((n / 8 + 255) / 256), 256, 0, stream>>>(s, d, (int)(n / 8));
  };

  // ---- P0: casts + combined bias + ln1 ----
  cast(Wq, Wqb, 2048 * 512);   cast(Wk, Wkb, 2048 * 512);
  cast(Wv, Wvb, 512 * 512);    cast(Wvv, Wvvb, 512 * 512);
  cast(Wo, Wob, 512 * 512);    cast(Wvo, Wvob, 512 * 512);
  cast(caw, cawb, 1536 * 512); cast(caow, caowb, 512 * 512);
  cast(casw, caswb, 512 * 512);cast(flv, flvb, 1024 * 512);
  cast(fw1, fw1b, 2048 * 1024);cast(fw2, fw2b, 1024 * 2048);
  cast(prompt, promptb, 512 * 512);
  cast(V, Vb, (size_t)12288 * 512);
  biascomb<<<4096, 256, 0, stream>>>(Db, rbf, mask, BIASCb);
  ln_kernel<<<4096, 256, 0, stream>>>(H, ln1g, ln1b, HNb, 512);

  // ---- P1: QKV + Vv projections ----
  gemm_bf16<<<dim3(16, 32), 256, 0, stream>>>(HNb, Wqb, bq, nullptr, nullptr, HQb, 4096, 2048, 512, 1 | 16);
  gemm_bf16<<<dim3(16, 32), 256, 0, stream>>>(HNb, Wkb, bk, nullptr, nullptr, HKb, 4096, 2048, 512, 1 | 16);
  gemm_bf16<<<dim3(4, 32), 256, 0, stream>>>(HNb, Wvb, bv, nullptr, nullptr, HVb, 4096, 512, 512, 1 | 16);
  gemm_bf16<<<dim3(4, 96), 256, 0, stream>>>(Vb, Wvvb, nullptr, nullptr, nullptr, VVTb, 12288, 512, 512, 16);

  // ---- P2: V^T layout build ----
  vt_build<<<dim3(16, 4, 32), 256, 0, stream>>>(HVb, VVTb, VT);

  // ---- P3: fused self-attention ----
  attn_mfma<<<dim3(16, 32), 256, 0, stream>>>(HQb, HKb, VT, BIASCb, HRESb, VRESb);

  // ---- P4: output projections + residuals ----
  gemm_bf16<<<dim3(4, 32), 256, 0, stream>>>(HRESb, Wob, bo, H, H1, nullptr, 4096, 512, 512, 1 | 2 | 8);
  gemm_bf16<<<dim3(4, 96), 256, 0, stream>>>(VRESb, Wvob, nullptr, V, VNEW, VNEWb, 12288, 512, 512, 2 | 8 | 16);

  // ---- P5: cross-attention projections (Q; K+V merged) ----
  ln_kernel<<<4096, 256, 0, stream>>>(H1, ln2g, ln2b, HN2b, 512);
  gemm_bf16<<<dim3(4, 32), 256, 0, stream>>>(HN2b, cawb, cab, nullptr, nullptr, QCb, 4096, 512, 512, 1 | 16);
  gemm_bf16<<<dim3(8, 4), 256, 0, stream>>>(promptb, cawb + 262144, cab + 512, nullptr, nullptr, KVCb, 512, 1024, 512, 1 | 16);

  // ---- P6: cross-attention (MFMA) ----
  attn_cross_mfma<<<dim3(16, 32), 256, 0, stream>>>(QCb, KVCb, COb);

  // ---- P7: cross-attention output path ----
  gemm_bf16<<<dim3(4, 32), 256, 0, stream>>>(COb, caowb, caob, nullptr, nullptr, CO2b, 4096, 512, 512, 1 | 16);
  gemm_bf16<<<dim3(4, 32), 256, 0, stream>>>(CO2b, caswb, casb, H1, H2, nullptr, 4096, 512, 512, 1 | 2 | 8);

  // ---- P8: FFN inputs ----
  gemm_bf16<<<dim3(8, 96), 256, 0, stream>>>(VNEWb, flvb, nullptr, nullptr, VP, nullptr, 12288, 1024, 512, 8);
  ln_kernel<<<4096, 256, 0, stream>>>(H2, ln3g, ln3b, SCALb, 1024);
  vnorm_kernel<<<8192, 256, 0, stream>>>(VP, SCALb);

  // ---- P9: FFN ----
  gemm_bf16<<<dim3(16, 32), 256, 0, stream>>>(SCALb, fw1b, fb1, nullptr, nullptr, HH1b, 4096, 2048, 1024, 1 | 4 | 16);
  gemm_bf16<<<dim3(8, 32), 256, 0, stream>>>(HH1b, fw2b, fb2, nullptr, SO, nullptr, 4096, 1024, 2048, 1 | 8);

  // ---- P10: final combine ----
  final_kernel<<<8192, 256, 0, stream>>>(SO, H2, VP, VNEW, out);

  (void)in_sizes; (void)n_in; (void)out_size; (void)ws_size; (void)prompt;
}

// Round 5
// 550.300 us; speedup vs baseline: 6.6458x; 1.1880x over previous
//
#include <hip/hip_runtime.h>
#include <cstdint>
#include <cstddef>

#define B_    4
#define N_    1024
#define P_    128
#define D_    512
#define NH_   8

typedef unsigned short ushort_t;
typedef short short8 __attribute__((ext_vector_type(8)));
typedef float f32x4 __attribute__((ext_vector_type(4)));
typedef ushort_t ushort4_t __attribute__((ext_vector_type(4)));

__device__ inline ushort_t f2bf(float f) {
  union { float fp; unsigned int u; } v; v.fp = f;
  unsigned int r = v.u + 0x7fffu + ((v.u >> 16) & 1u);
  return (ushort_t)(r >> 16);
}
__device__ inline float bf2f(ushort_t u) {
  union { unsigned int i; float f; } v; v.i = ((unsigned int)u) << 16;
  return v.f;
}

// direct global->LDS (16B per lane, wave-uniform LDS base + lane*16)
__device__ __forceinline__ void gll16(const ushort_t* g, ushort_t* l) {
  __builtin_amdgcn_global_load_lds(
      (const __attribute__((address_space(1))) void*)g,
      (__attribute__((address_space(3))) void*)l, 16, 0, 0);
}

// ---------------------------------------------------------------------------
// fused fp32->bf16 cast of all weights + prompt + V (one launch)
// ---------------------------------------------------------------------------
__device__ inline void cast8(const float* __restrict__ s, ushort_t* __restrict__ d,
                             unsigned i) {
  const float* sp = s + (size_t)i * 8;
  short8 o;
#pragma unroll
  for (int j = 0; j < 8; ++j) o[j] = (short)f2bf(sp[j]);
  *(short8*)(d + (size_t)i * 8) = o;
}

__global__ __launch_bounds__(256) void cast_fused(
    const float* s0, ushort_t* d0,  const float* s1, ushort_t* d1,
    const float* s2, ushort_t* d2,  const float* s3, ushort_t* d3,
    const float* s4, ushort_t* d4,  const float* s5, ushort_t* d5,
    const float* s6, ushort_t* d6,  const float* s7, ushort_t* d7,
    const float* s8, ushort_t* d8,  const float* s9, ushort_t* d9,
    const float* s10, ushort_t* d10, const float* s11, ushort_t* d11,
    const float* s12, ushort_t* d12, const float* s13, ushort_t* d13)
{
  unsigned i = blockIdx.x * 256 + threadIdx.x;
#define SEG(s, d, n8) if (i < (n8)) { cast8(s, d, i); return; } i -= (n8);
  SEG(s0, d0, 131072u)   // Wq
  SEG(s1, d1, 131072u)   // Wk
  SEG(s2, d2, 32768u)    // Wv
  SEG(s3, d3, 32768u)    // Wvv
  SEG(s4, d4, 32768u)    // Wo
  SEG(s5, d5, 32768u)    // Wvo
  SEG(s6, d6, 98304u)    // caw
  SEG(s7, d7, 32768u)    // caow
  SEG(s8, d8, 32768u)    // casw
  SEG(s9, d9, 65536u)    // flv
  SEG(s10, d10, 262144u) // fw1
  SEG(s11, d11, 262144u) // fw2
  SEG(s12, d12, 32768u)  // prompt
  SEG(s13, d13, 786432u) // V
#undef SEG
}

__global__ __launch_bounds__(256) void biasmerge(const float* __restrict__ bq,
                                                 const float* __restrict__ bk,
                                                 float* __restrict__ o)
{
  int i = blockIdx.x * 256 + threadIdx.x;
  o[i] = (i < 2048) ? bq[i] : bk[i - 2048];
}

// ---------------------------------------------------------------------------
// combined bias (bf16): out[b,n,m] = mask[b,m] ? rbf[b,0,n,m]+Db[b,n,m] : -1e30
// ---------------------------------------------------------------------------
__global__ __launch_bounds__(256) void biascomb(const float* __restrict__ Db,
                                                const float* __restrict__ rbf,
                                                const int* __restrict__ mask,
                                                ushort_t* __restrict__ out)
{
  size_t i = (size_t)blockIdx.x * 256 + threadIdx.x;
  size_t e = i * 4;
  int b  = (int)(e >> 20);
  int m0 = (int)(e & 1023);
  float4 r = *(const float4*)(rbf + e);
  float4 d = *(const float4*)(Db + e);
  const int* mp = mask + b * 1024 + m0;
  ushort4_t o;
  o.x = f2bf(mp[0] ? r.x + d.x : -1e30f);
  o.y = f2bf(mp[1] ? r.y + d.y : -1e30f);
  o.z = f2bf(mp[2] ? r.z + d.z : -1e30f);
  o.w = f2bf(mp[3] ? r.w + d.w : -1e30f);
  *(ushort4_t*)(out + e) = o;
}

// ---------------------------------------------------------------------------
// LayerNorm (fp32 in, bf16 out), one block per row of 512
// ---------------------------------------------------------------------------
__global__ __launch_bounds__(256) void ln_kernel(
    const float* __restrict__ x, const float* __restrict__ g,
    const float* __restrict__ bb, ushort_t* __restrict__ y, int ostride)
{
  int row = blockIdx.x;
  int t = threadIdx.x;
  const float* xr = x + (size_t)row * D_;
  float a = xr[t], c = xr[t + 256];
  float s = a + c, sq = a * a + c * c;
#pragma unroll
  for (int off = 32; off >= 1; off >>= 1) {
    s  += __shfl_xor(s, off);
    sq += __shfl_xor(sq, off);
  }
  __shared__ float red[8];
  int w = t >> 6, lane = t & 63;
  if (lane == 0) { red[w] = s; red[4 + w] = sq; }
  __syncthreads();
  float st  = red[0] + red[1] + red[2] + red[3];
  float sqt = red[4] + red[5] + red[6] + red[7];
  float mean = st * (1.0f / D_);
  float var  = sqt * (1.0f / D_) - mean * mean;
  float inv  = rsqrtf(var + 1e-5f);
  y[(size_t)row * ostride + t]       = f2bf((a - mean) * inv * g[t] + bb[t]);
  y[(size_t)row * ostride + t + 256] = f2bf((c - mean) * inv * g[t + 256] + bb[t + 256]);
}

// ---------------------------------------------------------------------------
// bf16 MFMA GEMM, m97-style: global_load_lds(16B) staging into linear
// [128][32] LDS tiles; pre-swizzled global source + swizzled ds_read
// (slot ^= (row>>1)&3) for ~2-way bank behavior.  128x128 tile, BK=32,
// 4 waves (2x2), wave = 64x64 via 4x4 16x16x32 frags.
// flags: 1=bias 2=res 4=silu 8=write fp32 16=write bf16
// ---------------------------------------------------------------------------
__global__ __launch_bounds__(256) void gemm_bf16(
    const ushort_t* __restrict__ A, const ushort_t* __restrict__ W,
    const float* __restrict__ bias, const float* __restrict__ res,
    float* __restrict__ Cf, ushort_t* __restrict__ Cb,
    int M, int N, int K, int flags)
{
  __shared__ __align__(16) ushort_t Al[128 * 32];
  __shared__ __align__(16) ushort_t Wl[128 * 32];
  const int t = threadIdx.x;
  const int wv = t >> 6, lane = t & 63, lr = lane & 15, lk = lane >> 4;
  const int wr = wv >> 1, wc = wv & 1;
  const size_t row0 = (size_t)blockIdx.y * 128;
  const size_t col0 = (size_t)blockIdx.x * 128;

  // staging: wave wv owns rows [32wv, 32wv+32) of both tiles (2 chunks each).
  // within a 1024B chunk, lane l -> row base+l/4, swizzled slot (l&3)^((l>>3)&3)
  const int srow = 32 * wv + (lane >> 2);
  const int scol = (((lane & 3) ^ ((lane >> 3) & 3))) * 8;
  const ushort_t* ApG = A + (row0 + srow) * (size_t)K + scol;
  const ushort_t* WpG = W + (col0 + srow) * (size_t)K + scol;
  ushort_t* AlD = Al + (size_t)(32 * wv) * 32;
  ushort_t* WlD = Wl + (size_t)(32 * wv) * 32;
  const size_t K16 = (size_t)16 * K;

  f32x4 acc[4][4];
#pragma unroll
  for (int i = 0; i < 4; ++i)
#pragma unroll
    for (int j = 0; j < 4; ++j) acc[i][j] = f32x4{0.f, 0.f, 0.f, 0.f};

  const int sx = (lr >> 1) & 3;   // read-side swizzle (lane-constant)

  for (int k0 = 0; k0 < K; k0 += 32) {
    __syncthreads();
    gll16(ApG + k0,       AlD);
    gll16(ApG + k0 + K16, AlD + 512);
    gll16(WpG + k0,       WlD);
    gll16(WpG + k0 + K16, WlD + 512);
    __syncthreads();   // compiler drains vmcnt before s_barrier -> data ready
    short8 af[4], bf[4];
#pragma unroll
    for (int i = 0; i < 4; ++i)
      af[i] = *(const short8*)&Al[(wr * 64 + i * 16 + lr) * 32 + ((lk ^ sx) << 3)];
#pragma unroll
    for (int j = 0; j < 4; ++j)
      bf[j] = *(const short8*)&Wl[(wc * 64 + j * 16 + lr) * 32 + ((lk ^ sx) << 3)];
#pragma unroll
    for (int i = 0; i < 4; ++i)
#pragma unroll
      for (int j = 0; j < 4; ++j)
        acc[i][j] = __builtin_amdgcn_mfma_f32_16x16x32_bf16(af[i], bf[j], acc[i][j], 0, 0, 0);
  }

  const int orow = wr * 64 + lk * 4, ocol = wc * 64 + lr;
#pragma unroll
  for (int i = 0; i < 4; ++i) {
#pragma unroll
    for (int j = 0; j < 4; ++j) {
      size_t colb = col0 + ocol + j * 16;
      float bv = (flags & 1) ? bias[colb] : 0.f;
#pragma unroll
      for (int r = 0; r < 4; ++r) {
        size_t rowg = row0 + orow + i * 16 + r;
        float v = acc[i][j][r] + bv;
        if (flags & 4) v = v / (1.f + __expf(-v));
        if (flags & 2) v += res[rowg * N + colb];
        if (flags & 8)  Cf[rowg * N + colb] = v;
        if (flags & 16) Cb[rowg * N + colb] = f2bf(v);
      }
    }
  }
}

// ---------------------------------------------------------------------------
// Build VT[b][h][dcat(256)][n(1024)] bf16 from HVb [4096][512] (dcat<64)
// and VVTb [12288][512] (dcat>=64).  LDS tile transpose.
// ---------------------------------------------------------------------------
__global__ __launch_bounds__(256) void vt_build(
    const ushort_t* __restrict__ HVb, const ushort_t* __restrict__ VVTb,
    ushort_t* __restrict__ VT)
{
  const int bh = blockIdx.z, b = bh >> 3, h = bh & 7;
  const int n0 = blockIdx.x * 64, dt = blockIdx.y;
  __shared__ __align__(16) ushort_t tile[64][72];
  const int t = threadIdx.x;
  {
    int r = t >> 2, c0 = (t & 3) * 16;
    const ushort_t* src = (dt == 0)
      ? HVb + ((size_t)(b * 1024 + n0 + r)) * 512 + h * 64 + c0
      : VVTb + (((size_t)(b * 1024 + n0 + r)) * 3 + (dt - 1)) * 512 + h * 64 + c0;
    *(short8*)&tile[r][c0]     = *(const short8*)src;
    *(short8*)&tile[r][c0 + 8] = *(const short8*)(src + 8);
  }
  __syncthreads();
  {
    int d = t >> 2, nc = (t & 3) * 16;
    short8 o0, o1;
#pragma unroll
    for (int i = 0; i < 8; ++i) { o0[i] = tile[nc + i][d]; o1[i] = tile[nc + 8 + i][d]; }
    ushort_t* dst = VT + ((size_t)bh * 256 + dt * 64 + d) * 1024 + n0 + nc;
    *(short8*)dst = o0;
    *(short8*)(dst + 8) = o1;
  }
}

// ---------------------------------------------------------------------------
// Fused self-attention, bf16 MFMA flash-style.  Block = (b,h, 64 q-rows),
// 4 waves x 16 q x full dcat=256.  KVBLK=32, 42.5 KB LDS -> 3 blocks/CU.
// Q/K from merged QK buffer [4096][4096] (Q cols 0..2047, K cols 2048+).
// ---------------------------------------------------------------------------
__global__ __launch_bounds__(256) void attn_mfma(
    const ushort_t* __restrict__ QKg, const ushort_t* __restrict__ VTg,
    const ushort_t* __restrict__ biasb,
    ushort_t* __restrict__ HRESb, ushort_t* __restrict__ VRESb)
{
  const int bh = blockIdx.y, b = bh >> 3, h = bh & 7;
  const int q0 = blockIdx.x * 64;
  const int t = threadIdx.x, w = t >> 6, lane = t & 63, lr = lane & 15, lk = lane >> 4;

  __shared__ __align__(16) ushort_t Kl[32][264];
  __shared__ __align__(16) ushort_t Vl[256][40];
  __shared__ __align__(16) ushort_t Pl[4][16][40];

  short8 qf[8];
  {
    const ushort_t* qb = QKg + ((size_t)(b * 1024 + q0 + w * 16 + lr)) * 4096 + h * 256;
#pragma unroll
    for (int s = 0; s < 8; ++s) qf[s] = *(const short8*)(qb + s * 32 + lk * 8);
  }
  f32x4 o[16];
#pragma unroll
  for (int i = 0; i < 16; ++i) o[i] = f32x4{0.f, 0.f, 0.f, 0.f};
  float mrow[4] = {-1e30f, -1e30f, -1e30f, -1e30f};
  float lsum[4] = {0.f, 0.f, 0.f, 0.f};
  const int qrow = q0 + w * 16 + lk * 4;

  const int krow = t >> 3, kc = (t & 7) * 32;
  const ushort_t* ksrc = QKg + ((size_t)(b * 1024 + krow)) * 4096 + 2048 + h * 256 + kc;
  const ushort_t* vsrc = VTg + ((size_t)bh * 256 + t) * 1024;
  const int vrot = (t >> 3) & 3;

  for (int k0 = 0; k0 < 1024; k0 += 32) {
    __syncthreads();
    {
      const ushort_t* ks = ksrc + (size_t)k0 * 4096;
#pragma unroll
      for (int c = 0; c < 4; ++c)
        *(short8*)&Kl[krow][kc + c * 8] = *(const short8*)(ks + c * 8);
#pragma unroll
      for (int c = 0; c < 4; ++c) {
        int cc = (c + vrot) & 3;
        *(short8*)&Vl[t][cc * 8] = *(const short8*)(vsrc + k0 + cc * 8);
      }
    }
    __syncthreads();

    // QK^T: S[16q][32k]
    f32x4 s2[2];
    s2[0] = f32x4{0.f, 0.f, 0.f, 0.f};
    s2[1] = f32x4{0.f, 0.f, 0.f, 0.f};
    __builtin_amdgcn_s_setprio(1);
#pragma unroll
    for (int ks = 0; ks < 8; ++ks) {
#pragma unroll
      for (int j = 0; j < 2; ++j) {
        short8 kf = *(const short8*)&Kl[j * 16 + lr][ks * 32 + lk * 8];
        s2[j] = __builtin_amdgcn_mfma_f32_16x16x32_bf16(qf[ks], kf, s2[j], 0, 0, 0);
      }
    }
    __builtin_amdgcn_s_setprio(0);

    // scale + bias (D-layout: row = lk*4+r, col = j*16+lr)
    float sv[2][4];
    const ushort_t* bp = biasb + ((size_t)b << 20) + (size_t)qrow * 1024 + k0 + lr;
#pragma unroll
    for (int r = 0; r < 4; ++r) {
      sv[0][r] = s2[0][r] * 0.0625f + bf2f(bp[r * 1024]);
      sv[1][r] = s2[1][r] * 0.0625f + bf2f(bp[r * 1024 + 16]);
    }
    // online softmax with defer-max (skip O-rescale when growth <= 8)
    float pm[4], need = -1e30f;
#pragma unroll
    for (int r = 0; r < 4; ++r) {
      float m2 = fmaxf(sv[0][r], sv[1][r]);
      m2 = fmaxf(m2, __shfl_xor(m2, 1));
      m2 = fmaxf(m2, __shfl_xor(m2, 2));
      m2 = fmaxf(m2, __shfl_xor(m2, 4));
      m2 = fmaxf(m2, __shfl_xor(m2, 8));
      pm[r] = m2;
      need = fmaxf(need, m2 - mrow[r]);
    }
    if (!__all(need <= 8.f)) {
#pragma unroll
      for (int r = 0; r < 4; ++r) {
        float mn = fmaxf(mrow[r], pm[r]);
        float al = __expf(mrow[r] - mn);
        mrow[r] = mn;
        lsum[r] *= al;
#pragma unroll
        for (int d = 0; d < 16; ++d) o[d][r] *= al;
      }
    }
#pragma unroll
    for (int r = 0; r < 4; ++r) {
      float p0 = __expf(sv[0][r] - mrow[r]);
      float p1 = __expf(sv[1][r] - mrow[r]);
      float rs = p0 + p1;
      rs += __shfl_xor(rs, 1); rs += __shfl_xor(rs, 2);
      rs += __shfl_xor(rs, 4); rs += __shfl_xor(rs, 8);
      lsum[r] += rs;
      Pl[w][lk * 4 + r][lr]      = f2bf(p0);
      Pl[w][lk * 4 + r][16 + lr] = f2bf(p1);
    }
    // PV (Pl is wave-private: no block barrier needed)
    short8 pf = *(const short8*)&Pl[w][lr][lk * 8];
    __builtin_amdgcn_s_setprio(1);
#pragma unroll
    for (int d = 0; d < 16; ++d) {
      short8 vf = *(const short8*)&Vl[d * 16 + lr][lk * 8];
      o[d] = __builtin_amdgcn_mfma_f32_16x16x32_bf16(pf, vf, o[d], 0, 0, 0);
    }
    __builtin_amdgcn_s_setprio(0);
  }

  float inv[4];
#pragma unroll
  for (int r = 0; r < 4; ++r) inv[r] = 1.f / lsum[r];
#pragma unroll
  for (int d = 0; d < 16; ++d) {
    int dcat = d * 16 + lr;
#pragma unroll
    for (int r = 0; r < 4; ++r) {
      float v = o[d][r] * inv[r];
      int n = qrow + r;
      if (dcat < 64)
        HRESb[((size_t)b * 1024 + n) * 512 + h * 64 + dcat] = f2bf(v);
      else {
        int c = (dcat - 64) >> 6, jj = (dcat - 64) & 63;
        VRESb[(((size_t)b * 1024 + n) * 3 + c) * 512 + h * 64 + jj] = f2bf(v);
      }
    }
  }
}

// ---------------------------------------------------------------------------
// Cross-attention, bf16 MFMA.  Block = (b,h, 64 q-rows), 4 waves x 16 q.
// ---------------------------------------------------------------------------
__global__ __launch_bounds__(256) void attn_cross_mfma(
    const ushort_t* __restrict__ Qb, const ushort_t* __restrict__ KVb,
    ushort_t* __restrict__ COb)
{
  const int bh = blockIdx.y, b = bh >> 3, h = bh & 7;
  const int q0 = blockIdx.x * 64;
  const int t = threadIdx.x, w = t >> 6, lane = t & 63, lr = lane & 15, lk = lane >> 4;

  __shared__ __align__(16) ushort_t Kl[128][72];
  __shared__ __align__(16) ushort_t Vt[64][136];
  __shared__ __align__(16) ushort_t Pl[4][16][136];

  {
    int p = t >> 1, c0 = (t & 1) * 32;
    const ushort_t* kp = KVb + ((size_t)b * 128 + p) * 1024 + h * 64 + c0;
#pragma unroll
    for (int i = 0; i < 4; ++i) {
      short8 kv = *(const short8*)(kp + i * 8);
      *(short8*)&Kl[p][c0 + i * 8] = kv;
      short8 vv = *(const short8*)(kp + 512 + i * 8);
#pragma unroll
      for (int jj = 0; jj < 8; ++jj) Vt[c0 + i * 8 + jj][p] = (ushort_t)vv[jj];
    }
  }
  __syncthreads();

  short8 qf[2];
  {
    const ushort_t* qp = Qb + ((size_t)b * 1024 + q0 + w * 16 + lr) * 512 + h * 64;
    qf[0] = *(const short8*)(qp + lk * 8);
    qf[1] = *(const short8*)(qp + 32 + lk * 8);
  }

  f32x4 s[8];
#pragma unroll
  for (int j = 0; j < 8; ++j) s[j] = f32x4{0.f, 0.f, 0.f, 0.f};
#pragma unroll
  for (int ks = 0; ks < 2; ++ks)
#pragma unroll
    for (int j = 0; j < 8; ++j) {
      short8 kf = *(const short8*)&Kl[j * 16 + lr][ks * 32 + lk * 8];
      s[j] = __builtin_amdgcn_mfma_f32_16x16x32_bf16(qf[ks], kf, s[j], 0, 0, 0);
    }

  float linv[4];
#pragma unroll
  for (int r = 0; r < 4; ++r) {
    float sc[8];
#pragma unroll
    for (int j = 0; j < 8; ++j) sc[j] = s[j][r] * 0.125f;
    float mx = sc[0];
#pragma unroll
    for (int j = 1; j < 8; ++j) mx = fmaxf(mx, sc[j]);
    mx = fmaxf(mx, __shfl_xor(mx, 1));
    mx = fmaxf(mx, __shfl_xor(mx, 2));
    mx = fmaxf(mx, __shfl_xor(mx, 4));
    mx = fmaxf(mx, __shfl_xor(mx, 8));
    float rs = 0.f;
#pragma unroll
    for (int j = 0; j < 8; ++j) {
      float p = __expf(sc[j] - mx);
      rs += p;
      Pl[w][lk * 4 + r][j * 16 + lr] = f2bf(p);
    }
    rs += __shfl_xor(rs, 1); rs += __shfl_xor(rs, 2);
    rs += __shfl_xor(rs, 4); rs += __shfl_xor(rs, 8);
    linv[r] = 1.f / rs;
  }
  __syncthreads();

  f32x4 o[4];
#pragma unroll
  for (int d = 0; d < 4; ++d) o[d] = f32x4{0.f, 0.f, 0.f, 0.f};
#pragma unroll
  for (int ks = 0; ks < 4; ++ks) {
    short8 pf = *(const short8*)&Pl[w][lr][ks * 32 + lk * 8];
#pragma unroll
    for (int d = 0; d < 4; ++d) {
      short8 vf = *(const short8*)&Vt[d * 16 + lr][ks * 32 + lk * 8];
      o[d] = __builtin_amdgcn_mfma_f32_16x16x32_bf16(pf, vf, o[d], 0, 0, 0);
    }
  }

#pragma unroll
  for (int d = 0; d < 4; ++d)
#pragma unroll
    for (int r = 0; r < 4; ++r) {
      int n = q0 + w * 16 + lk * 4 + r;
      COb[((size_t)b * 1024 + n) * 512 + h * 64 + d * 16 + lr] = f2bf(o[d][r] * linv[r]);
    }
}

// ---------------------------------------------------------------------------
// norms of V1 (bf16 VP) -> SCALb cols 512..1023 (bf16)
// ---------------------------------------------------------------------------
__global__ __launch_bounds__(256) void vnorm_kernel(
    const ushort_t* __restrict__ Vp, ushort_t* __restrict__ scal)
{
  size_t i = (size_t)blockIdx.x * 256 + threadIdx.x;
  size_t bn = i >> 9; int d = (int)(i & 511);
  size_t base = bn * 3 * 1024 + d;
  float a = bf2f(Vp[base]);
  float b = bf2f(Vp[base + 1024]);
  float c = bf2f(Vp[base + 2048]);
  scal[bn * 1024 + 512 + d] = f2bf(sqrtf(a * a + b * b + c * c));
}

// ---------------------------------------------------------------------------
// final: H = so[:,:512] + H2 ; V = so[:,512:][...,None,:] * V2(bf16) + Vnew
// ---------------------------------------------------------------------------
__global__ __launch_bounds__(256) void final_kernel(
    const float* __restrict__ so, const float* __restrict__ H2,
    const ushort_t* __restrict__ Vp, const float* __restrict__ Vnew,
    float* __restrict__ out)
{
  size_t i = (size_t)blockIdx.x * 256 + threadIdx.x;
  size_t bn = i >> 9; int d = (int)(i & 511);
  out[bn * 512 + d] = so[bn * 1024 + d] + H2[bn * 512 + d];
  float vu = so[bn * 1024 + 512 + d];
  float* outV = out + (size_t)B_ * N_ * D_;
#pragma unroll
  for (int c = 0; c < 3; ++c) {
    size_t vi = (bn * 3 + c) * 512 + d;
    outV[vi] = vu * bf2f(Vp[(bn * 3 + c) * 1024 + 512 + d]) + Vnew[vi];
  }
}

// ---------------------------------------------------------------------------
extern "C" void kernel_launch(void* const* d_in, const int* in_sizes, int n_in,
                              void* d_out, int out_size, void* d_ws, size_t ws_size,
                              hipStream_t stream)
{
  const float* H      = (const float*)d_in[0];
  const float* V      = (const float*)d_in[1];
  const float* Db     = (const float*)d_in[2];
  const float* rbf    = (const float*)d_in[3];
  const float* prompt = (const float*)d_in[4];
  const float* Wq  = (const float*)d_in[5];
  const float* bq  = (const float*)d_in[6];
  const float* Wk  = (const float*)d_in[7];
  const float* bk  = (const float*)d_in[8];
  const float* Wv  = (const float*)d_in[9];
  const float* bv  = (const float*)d_in[10];
  const float* Wvv = (const float*)d_in[11];
  const float* Wo  = (const float*)d_in[12];
  const float* bo  = (const float*)d_in[13];
  const float* Wvo = (const float*)d_in[14];
  const float* ln1g = (const float*)d_in[15];
  const float* ln1b = (const float*)d_in[16];
  const float* caw  = (const float*)d_in[17];
  const float* cab  = (const float*)d_in[18];
  const float* caow = (const float*)d_in[19];
  const float* caob = (const float*)d_in[20];
  const float* casw = (const float*)d_in[21];
  const float* casb = (const float*)d_in[22];
  const float* ln2g = (const float*)d_in[23];
  const float* ln2b = (const float*)d_in[24];
  const float* flv  = (const float*)d_in[25];
  const float* fw1  = (const float*)d_in[26];
  const float* fb1  = (const float*)d_in[27];
  const float* fw2  = (const float*)d_in[28];
  const float* fb2  = (const float*)d_in[29];
  const float* ln3g = (const float*)d_in[30];
  const float* ln3b = (const float*)d_in[31];
  const int*   mask = (const int*)d_in[32];

  char* wsb = (char*)d_ws;
  float* out = (float*)d_out;

  // offsets in 0.5 MiB units; phase lifetimes annotated; max 277 u = 138.5 MiB
#define HMB(x) ((size_t)(x) << 19)
  ushort_t* Wqkb  = (ushort_t*)(wsb + HMB(0));    // 8 u  (Wq rows 0..2047, Wk rows 2048..)
  ushort_t* Wvb   = (ushort_t*)(wsb + HMB(8));
  ushort_t* Wvvb  = (ushort_t*)(wsb + HMB(9));
  ushort_t* Wob   = (ushort_t*)(wsb + HMB(10));
  ushort_t* Wvob  = (ushort_t*)(wsb + HMB(11));
  ushort_t* cawb  = (ushort_t*)(wsb + HMB(12));
  ushort_t* caowb = (ushort_t*)(wsb + HMB(15));
  ushort_t* caswb = (ushort_t*)(wsb + HMB(16));
  ushort_t* flvb  = (ushort_t*)(wsb + HMB(17));
  ushort_t* fw1b  = (ushort_t*)(wsb + HMB(19));
  ushort_t* fw2b  = (ushort_t*)(wsb + HMB(27));
  ushort_t* promptb = (ushort_t*)(wsb + HMB(35));
  float*    BQK   = (float*)   (wsb + HMB(36));   // merged bq|bk, 16 KB
  ushort_t* HQKb  = (ushort_t*)(wsb + HMB(37));   // 64 u, P1-P3 (37..101)
  float*    VNEW  = (float*)   (wsb + HMB(37));   // 48 u, P4-end (37..85)
  float*    H2    = (float*)   (wsb + HMB(85));   // 16 u, P7-end (85..101)
  ushort_t* HNb   = (ushort_t*)(wsb + HMB(101));  // 8 u, P0-P1
  ushort_t* VT    = (ushort_t*)(wsb + HMB(101));  // 32 u, P2-P3 (101..133)
  ushort_t* QCb   = (ushort_t*)(wsb + HMB(101));  // 8 u, P5-P6
  ushort_t* KVCb  = (ushort_t*)(wsb + HMB(109));  // 2 u, P5-P6
  ushort_t* SCALb = (ushort_t*)(wsb + HMB(101));  // 16 u, P8-P9 (101..117)
  ushort_t* Vb    = (ushort_t*)(wsb + HMB(133));  // 24 u, P0-P1 (133..157)
  ushort_t* HRESb = (ushort_t*)(wsb + HMB(133));  // 8 u, P3-P4
  ushort_t* HN2b  = (ushort_t*)(wsb + HMB(133));  // 8 u, P5
  ushort_t* VPb   = (ushort_t*)(wsb + HMB(133));  // 48 u, P8-end (133..181)
  ushort_t* VRESb = (ushort_t*)(wsb + HMB(141));  // 24 u, P3-P4 (141..165)
  ushort_t* COb   = (ushort_t*)(wsb + HMB(141));  // 8 u, P6-P7
  ushort_t* CO2b  = (ushort_t*)(wsb + HMB(149));  // 8 u, P7
  ushort_t* HVb   = (ushort_t*)(wsb + HMB(157));  // 8 u, P1-P2
  ushort_t* VVTb  = (ushort_t*)(wsb + HMB(165));  // 24 u, P1-P2 (165..189)
  float*    H1    = (float*)   (wsb + HMB(165));  // 16 u, P4-P7 (165..181)
  ushort_t* BIASCb= (ushort_t*)(wsb + HMB(189));  // 16 u, P0-P3 (189..205)
  float*    SO    = (float*)   (wsb + HMB(189));  // 32 u, P9-end (189..221)
  ushort_t* VNEWb = (ushort_t*)(wsb + HMB(221));  // 24 u, P4-P8 (221..245)
  ushort_t* HH1b  = (ushort_t*)(wsb + HMB(245));  // 32 u, P9 (245..277) -- was 117: clobbered VPb (r4 bug)

  // ---- P0 ----
  cast_fused<<<7680, 256, 0, stream>>>(
      Wq, Wqkb, Wk, Wqkb + (size_t)2048 * 512, Wv, Wvb, Wvv, Wvvb, Wo, Wob,
      Wvo, Wvob, caw, cawb, caow, caowb, casw, caswb, flv, flvb,
      fw1, fw1b, fw2, fw2b, prompt, promptb, V, Vb);
  biasmerge<<<16, 256, 0, stream>>>(bq, bk, BQK);
  biascomb<<<4096, 256, 0, stream>>>(Db, rbf, mask, BIASCb);
  ln_kernel<<<4096, 256, 0, stream>>>(H, ln1g, ln1b, HNb, 512);

  // ---- P1: merged QK + V + Vv projections ----
  gemm_bf16<<<dim3(32, 32), 256, 0, stream>>>(HNb, Wqkb, BQK, nullptr, nullptr, HQKb, 4096, 4096, 512, 1 | 16);
  gemm_bf16<<<dim3(4, 32), 256, 0, stream>>>(HNb, Wvb, bv, nullptr, nullptr, HVb, 4096, 512, 512, 1 | 16);
  gemm_bf16<<<dim3(4, 96), 256, 0, stream>>>(Vb, Wvvb, nullptr, nullptr, nullptr, VVTb, 12288, 512, 512, 16);

  // ---- P2: V^T layout build ----
  vt_build<<<dim3(16, 4, 32), 256, 0, stream>>>(HVb, VVTb, VT);

  // ---- P3: fused self-attention ----
  attn_mfma<<<dim3(16, 32), 256, 0, stream>>>(HQKb, VT, BIASCb, HRESb, VRESb);

  // ---- P4: output projections + residuals ----
  gemm_bf16<<<dim3(4, 32), 256, 0, stream>>>(HRESb, Wob, bo, H, H1, nullptr, 4096, 512, 512, 1 | 2 | 8);
  gemm_bf16<<<dim3(4, 96), 256, 0, stream>>>(VRESb, Wvob, nullptr, V, VNEW, VNEWb, 12288, 512, 512, 2 | 8 | 16);

  // ---- P5: cross-attention projections ----
  ln_kernel<<<4096, 256, 0, stream>>>(H1, ln2g, ln2b, HN2b, 512);
  gemm_bf16<<<dim3(4, 32), 256, 0, stream>>>(HN2b, cawb, cab, nullptr, nullptr, QCb, 4096, 512, 512, 1 | 16);
  gemm_bf16<<<dim3(8, 4), 256, 0, stream>>>(promptb, cawb + 262144, cab + 512, nullptr, nullptr, KVCb, 512, 1024, 512, 1 | 16);

  // ---- P6: cross-attention ----
  attn_cross_mfma<<<dim3(16, 32), 256, 0, stream>>>(QCb, KVCb, COb);

  // ---- P7: cross-attention output path ----
  gemm_bf16<<<dim3(4, 32), 256, 0, stream>>>(COb, caowb, caob, nullptr, nullptr, CO2b, 4096, 512, 512, 1 | 16);
  gemm_bf16<<<dim3(4, 32), 256, 0, stream>>>(CO2b, caswb, casb, H1, H2, nullptr, 4096, 512, 512, 1 | 2 | 8);

  // ---- P8: FFN inputs ----
  gemm_bf16<<<dim3(8, 96), 256, 0, stream>>>(VNEWb, flvb, nullptr, nullptr, nullptr, VPb, 12288, 1024, 512, 16);
  ln_kernel<<<4096, 256, 0, stream>>>(H2, ln3g, ln3b, SCALb, 1024);
  vnorm_kernel<<<8192, 256, 0, stream>>>(VPb, SCALb);

  // ---- P9: FFN ----
  gemm_bf16<<<dim3(16, 32), 256, 0, stream>>>(SCALb, fw1b, fb1, nullptr, nullptr, HH1b, 4096, 2048, 1024, 1 | 4 | 16);
  gemm_bf16<<<dim3(8, 32), 256, 0, stream>>>(HH1b, fw2b, fb2, nullptr, SO, nullptr, 4096, 1024, 2048, 1 | 8);

  // ---- P10: final combine ----
  final_kernel<<<8192, 256, 0, stream>>>(SO, H2, VPb, VNEW, out);

  (void)in_sizes; (void)n_in; (void)out_size; (void)ws_size;
}